// Round 2
// baseline (417.175 us; speedup 1.0000x reference)
//
#include <hip/hip_runtime.h>
#include <hip/hip_bf16.h>
#include <math.h>

#define DEVINL __device__ __forceinline__

typedef __bf16 bf16x8 __attribute__((ext_vector_type(8)));
typedef short short8_t __attribute__((ext_vector_type(8)));
typedef float f32x4 __attribute__((ext_vector_type(4)));
typedef unsigned short u16;
typedef unsigned int u32;

#define B_ 16
#define L_ 2048
#define DIM_ 256
#define BL_ (B_*L_)
#define NSPLIT 4
#define KVCHUNK (L_/NSPLIT)

DEVINL u16 f2bf(float f){
  __hip_bfloat16 h = __float2bfloat16(f);
  return __builtin_bit_cast(u16, h);
}
DEVINL float bf2f(u16 u){
  __hip_bfloat16 h = __builtin_bit_cast(__hip_bfloat16, u);
  return __bfloat162float(h);
}
DEVINL float siluf(float x){ return x / (1.f + __expf(-x)); }
DEVINL f32x4 mfma16(bf16x8 a, bf16x8 b, f32x4 c){
  return __builtin_amdgcn_mfma_f32_16x16x32_bf16(a, b, c, 0, 0, 0);
}
DEVINL bf16x8 ld_bf8(const u16* p){
  return __builtin_bit_cast(bf16x8, *(const short8_t*)p);
}

// ---------------- P1: weight prep (transpose to [n][k] bf16) ----------------
__global__ __launch_bounds__(256) void prep_weights(
    const float* __restrict__ w_h, const float* __restrict__ w_qk,
    const float* __restrict__ w_o, const float* __restrict__ w_p,
    const float* __restrict__ b_h, const float* __restrict__ b_qk,
    u16* __restrict__ wT1, u16* __restrict__ woT,
    u16* __restrict__ wp_bf, float* __restrict__ bias384){
  int idx = blockIdx.x*256 + threadIdx.x;
  const int total = 384*256 + 256*128 + 512*256 + 384;
  for (; idx < total; idx += gridDim.x*256){
    int i = idx;
    if (i < 384*256){
      int n = i >> 8, k = i & 255;
      float v = (n < 256) ? w_h[k*256 + n] : w_qk[k*128 + (n-256)];
      wT1[i] = f2bf(v);
    } else if ((i -= 384*256) < 256*128){
      int n = i >> 7, k = i & 127;
      woT[i] = f2bf(w_o[k*256 + n]);
    } else if ((i -= 256*128) < 512*256){
      wp_bf[i] = f2bf(w_p[i]);
    } else {
      i -= 512*256;
      bias384[i] = (i < 256) ? b_h[i] : b_qk[i-256];
    }
  }
}

// ---------------- P2: rope tables ----------------
__global__ __launch_bounds__(256) void prep_rope(float* __restrict__ ctab, float* __restrict__ stab){
  int idx = blockIdx.x*256 + threadIdx.x; // 2048*64
  if (idx >= 2048*64) return;
  int l = idx >> 6, f = idx & 63;
  float inv = powf(10000.f, -(float)(2*f) * (1.f/128.f));
  float ang = (float)l * inv;
  ctab[idx] = cosf(ang);
  stab[idx] = sinf(ang);
}

// ---------------- K1: layernorm (b,c,l)->bf16 (b,l,c) ----------------
__global__ __launch_bounds__(256) void ln_kernel(const float* __restrict__ x,
    const float* __restrict__ ln_g, const float* __restrict__ ln_b,
    u16* __restrict__ normed){
  __shared__ float xs[256][65];
  __shared__ float redsum[4][64], redsq[4][64];
  __shared__ float mu_s[64], rs_s[64];
  int b = blockIdx.y, lt = blockIdx.x;
  int tid = threadIdx.x;
  int tx = tid & 63, ty = tid >> 6;
  size_t xbase = (size_t)b*DIM_*L_ + (size_t)lt*64;
  float s = 0.f, s2 = 0.f;
  for (int c = ty; c < 256; c += 4){
    float v = x[xbase + (size_t)c*L_ + tx];
    xs[c][tx] = v;
    s += v; s2 += v*v;
  }
  redsum[ty][tx] = s; redsq[ty][tx] = s2;
  __syncthreads();
  if (ty == 0){
    float ss = redsum[0][tx]+redsum[1][tx]+redsum[2][tx]+redsum[3][tx];
    float qq = redsq[0][tx]+redsq[1][tx]+redsq[2][tx]+redsq[3][tx];
    float mu = ss * (1.f/256.f);
    float var = qq * (1.f/256.f) - mu*mu;
    mu_s[tx] = mu;
    rs_s[tx] = rsqrtf(var + 1e-5f);
  }
  __syncthreads();
  for (int i = 0; i < 8; i++){
    int chunk = tid + 256*i;
    int l = chunk >> 5, c0 = (chunk & 31) * 8;
    float mu = mu_s[l], rs = rs_s[l];
    short8_t outv;
    #pragma unroll
    for (int j = 0; j < 8; j++){
      int c = c0 + j;
      float v = (xs[c][l] - mu) * rs * ln_g[c] + ln_b[c];
      outv[j] = (short)f2bf(v);
    }
    *(short8_t*)&normed[((size_t)(b*L_) + lt*64 + l)*256 + c0] = outv;
  }
}

// ---------------- K2: GEMM1 normed @ [w_h | w_qk] + bias -> hidz bf16 (b,l,384)
__global__ __launch_bounds__(256) void gemm_hid(const u16* __restrict__ normed,
    const u16* __restrict__ wT1, const float* __restrict__ bias384,
    u16* __restrict__ hidz){
  __shared__ u16 atile[64*256];
  int b = blockIdx.y, lt = blockIdx.x;
  int tid = threadIdx.x;
  for (int i = 0; i < 8; i++){
    int chunk = tid + 256*i;
    int row = chunk >> 5, kc = chunk & 31;
    int byte = (row*512 + kc*16) ^ ((row & 7) << 4);
    *(short8_t*)((char*)atile + byte) =
        *(const short8_t*)&normed[((size_t)(b*L_) + lt*64 + row)*256 + kc*8];
  }
  __syncthreads();
  int lane = tid & 63, wave = tid >> 6;
  int l15 = lane & 15, lg = lane >> 4;
  int n0 = wave * 96;
  f32x4 zero = {0.f,0.f,0.f,0.f};
  f32x4 acc[4][6];
  for (int m=0;m<4;m++) for (int n=0;n<6;n++) acc[m][n]=zero;
  for (int ks = 0; ks < 8; ks++){
    bf16x8 a[4];
    #pragma unroll
    for (int m = 0; m < 4; m++){
      int row = m*16 + l15;
      int byte = (row*512 + ks*64 + lg*16) ^ ((row & 7) << 4);
      a[m] = __builtin_bit_cast(bf16x8, *(const short8_t*)((char*)atile + byte));
    }
    #pragma unroll
    for (int n = 0; n < 6; n++){
      int col = n0 + n*16 + l15;
      bf16x8 bfrag = ld_bf8(&wT1[col*256 + ks*32 + lg*8]);
      #pragma unroll
      for (int m = 0; m < 4; m++)
        acc[m][n] = mfma16(a[m], bfrag, acc[m][n]);
    }
  }
  for (int n = 0; n < 6; n++){
    int col = n0 + n*16 + l15;
    float bias = bias384[col];
    for (int m = 0; m < 4; m++)
      #pragma unroll
      for (int r = 0; r < 4; r++){
        size_t row = (size_t)(b*L_) + lt*64 + m*16 + lg*4 + r;
        hidz[row*384 + col] = f2bf(acc[m][n][r] + bias);
      }
  }
}

// ---------------- K3: pointwise silu / rope -> u, vT, q (pre-scaled 1/L), k ----
__global__ __launch_bounds__(256) void pointwise_kernel(const u16* __restrict__ hidz,
    const float* __restrict__ ctab, const float* __restrict__ stab,
    const float* __restrict__ gamma, const float* __restrict__ beta,
    float* __restrict__ u, u16* __restrict__ vT,
    u16* __restrict__ qm, u16* __restrict__ km){
  __shared__ u16 vs[64][130];
  int b = blockIdx.y, lt = blockIdx.x;
  int tid = threadIdx.x;
  size_t rowbase = (size_t)(b*L_) + lt*64;
  for (int i = 0; i < 32; i++){
    int idx = tid + 256*i;
    int l = idx >> 7, d = idx & 127;
    size_t row = rowbase + l;
    u[row*128 + d] = siluf(bf2f(hidz[row*384 + 128 + d]));
    vs[l][d] = hidz[row*384 + d];
  }
  __syncthreads();
  for (int i = 0; i < 4; i++){
    int chunk = tid + 256*i;
    int d = chunk >> 3, lc = (chunk & 7)*8;
    short8_t vv;
    #pragma unroll
    for (int j = 0; j < 8; j++)
      vv[j] = (short)f2bf(siluf(bf2f(vs[lc + j][d])));
    *(short8_t*)&vT[((size_t)b*128 + d)*2048 + lt*64 + lc] = vv;
  }
  const float inv_L = 1.f/(float)L_;
  for (int i = 0; i < 16; i++){
    int idx = tid + 256*i;
    int l = idx >> 6, f = idx & 63;
    size_t row = rowbase + l;
    u32 zz = *(const u32*)&hidz[row*384 + 256 + 2*f];
    float z1 = siluf(bf2f((u16)(zz & 0xffffu)));
    float z2 = siluf(bf2f((u16)(zz >> 16)));
    int gl = lt*64 + l;
    float c = ctab[gl*64 + f], s = stab[gl*64 + f];
    float q1 = z1*gamma[2*f]   + beta[2*f];
    float q2 = z2*gamma[2*f+1] + beta[2*f+1];
    // pre-scale q by 1/L so attention scores need no per-element scaling
    u32 qp = (u32)f2bf((q1*c - q2*s)*inv_L) | ((u32)f2bf((q1*s + q2*c)*inv_L) << 16);
    *(u32*)&qm[row*128 + 2*f] = qp;
    float k1 = z1*gamma[128 + 2*f]   + beta[128 + 2*f];
    float k2 = z2*gamma[128 + 2*f+1] + beta[128 + 2*f+1];
    u32 kp = (u32)f2bf(k1*c - k2*s) | ((u32)f2bf(k1*s + k2*c) << 16);
    *(u32*)&km[row*128 + 2*f] = kp;
  }
}

// ---------------- K4: flash attention, split-KV partials ----------------
__global__ __launch_bounds__(256) void attn_split(const u16* __restrict__ qm,
    const u16* __restrict__ km, const u16* __restrict__ vT,
    u16* __restrict__ o_part, float* __restrict__ ml){
  __shared__ u16 pbuf[4][16][32];
  int b = blockIdx.y, qt = blockIdx.x, z = blockIdx.z;
  int tid = threadIdx.x;
  int lane = tid & 63, wave = tid >> 6;
  int l15 = lane & 15, lg = lane >> 4;
  int qrow0 = qt*64 + wave*16;
  size_t qbase = ((size_t)(b*L_) + qrow0 + l15) * 128;
  bf16x8 qf[4];
  #pragma unroll
  for (int ks = 0; ks < 4; ks++)
    qf[ks] = ld_bf8(&qm[qbase + ks*32 + lg*8]);
  f32x4 zero = {0.f,0.f,0.f,0.f};
  f32x4 o[8];
  #pragma unroll
  for (int n = 0; n < 8; n++) o[n] = zero;
  float m[4], lsum[4];
  #pragma unroll
  for (int r = 0; r < 4; r++){ m[r] = -1e30f; lsum[r] = 0.f; }
  const u16* kb = km + (size_t)(b*L_)*128;
  const u16* vb = vT + (size_t)b*128*2048;
  const int j_lo = z*KVCHUNK, j_hi = j_lo + KVCHUNK;
  for (int j0 = j_lo; j0 < j_hi; j0 += 32){
    f32x4 s0 = zero, s1 = zero;
    #pragma unroll
    for (int ks = 0; ks < 4; ks++){
      bf16x8 k0 = ld_bf8(&kb[(size_t)(j0 + l15)*128 + ks*32 + lg*8]);
      bf16x8 k1 = ld_bf8(&kb[(size_t)(j0 + 16 + l15)*128 + ks*32 + lg*8]);
      s0 = mfma16(qf[ks], k0, s0);
      s1 = mfma16(qf[ks], k1, s1);
    }
    float corr[4];
    #pragma unroll
    for (int r = 0; r < 4; r++){
      float t = fmaxf(s0[r], s1[r]);
      t = fmaxf(t, __shfl_xor(t, 1));
      t = fmaxf(t, __shfl_xor(t, 2));
      t = fmaxf(t, __shfl_xor(t, 4));
      t = fmaxf(t, __shfl_xor(t, 8));
      float mn = fmaxf(m[r], t);
      float cr = __expf(m[r] - mn);
      corr[r] = cr;
      m[r] = mn;
      float p0 = __expf(s0[r] - mn), p1 = __expf(s1[r] - mn);
      lsum[r] = lsum[r]*cr + (p0 + p1);   // per-lane partial; reduced after loop
      s0[r] = p0; s1[r] = p1;
    }
    #pragma unroll
    for (int n = 0; n < 8; n++)
      #pragma unroll
      for (int r = 0; r < 4; r++)
        o[n][r] *= corr[r];
    #pragma unroll
    for (int r = 0; r < 4; r++){
      int rw = lg*4 + r;
      pbuf[wave][rw][l15]      = f2bf(s0[r]);
      pbuf[wave][rw][l15 + 16] = f2bf(s1[r]);
    }
    bf16x8 pa = __builtin_bit_cast(bf16x8, *(const short8_t*)&pbuf[wave][l15][lg*8]);
    #pragma unroll
    for (int n = 0; n < 8; n++){
      bf16x8 vf = ld_bf8(&vb[(size_t)(n*16 + l15)*2048 + j0 + lg*8]);
      o[n] = mfma16(pa, vf, o[n]);
    }
  }
  // finish per-row l: reduce per-lane partials across the 16 k-columns
  #pragma unroll
  for (int r = 0; r < 4; r++){
    float ls = lsum[r];
    ls += __shfl_xor(ls, 1);
    ls += __shfl_xor(ls, 2);
    ls += __shfl_xor(ls, 4);
    ls += __shfl_xor(ls, 8);
    lsum[r] = ls;
  }
  #pragma unroll
  for (int r = 0; r < 4; r++){
    size_t rowL = (size_t)(b*L_) + qrow0 + lg*4 + r;
    size_t obase = ((size_t)z*BL_ + rowL)*128;
    #pragma unroll
    for (int n = 0; n < 8; n++)
      o_part[obase + n*16 + l15] = f2bf(o[n][r]);
    if (l15 == 0){
      ml[((size_t)z*BL_ + rowL)*2]     = m[r];
      ml[((size_t)z*BL_ + rowL)*2 + 1] = lsum[r];
    }
  }
}

// ---------------- K4b: combine split partials ----------------
__global__ __launch_bounds__(256) void attn_combine(const u16* __restrict__ o_part,
    const float* __restrict__ ml, float* __restrict__ attnO){
  int tid = threadIdx.x;
  int row = blockIdx.x*8 + (tid >> 5);
  int d0 = (tid & 31)*4;
  float m_s[NSPLIT], l_s[NSPLIT];
  float M = -1e30f;
  #pragma unroll
  for (int s = 0; s < NSPLIT; s++){
    m_s[s] = ml[((size_t)s*BL_ + row)*2];
    l_s[s] = ml[((size_t)s*BL_ + row)*2 + 1];
    M = fmaxf(M, m_s[s]);
  }
  float Lt = 0.f, w[NSPLIT];
  #pragma unroll
  for (int s = 0; s < NSPLIT; s++){ w[s] = __expf(m_s[s] - M); Lt += l_s[s]*w[s]; }
  float ax=0.f, ay=0.f, az=0.f, aw=0.f;
  #pragma unroll
  for (int s = 0; s < NSPLIT; s++){
    uint2 pk = *(const uint2*)&o_part[((size_t)s*BL_ + row)*128 + d0];
    ax += w[s]*bf2f((u16)(pk.x & 0xffffu));
    ay += w[s]*bf2f((u16)(pk.x >> 16));
    az += w[s]*bf2f((u16)(pk.y & 0xffffu));
    aw += w[s]*bf2f((u16)(pk.y >> 16));
  }
  float inv = 1.f/Lt;
  float4 outv = {ax*inv, ay*inv, az*inv, aw*inv};
  *(float4*)&attnO[(size_t)row*128 + d0] = outv;
}

// ---------------- K5: (u*V) @ w_o + b_o -> outbl bf16 (b,l,256) ----------------
__global__ __launch_bounds__(256) void gemm_out(const float* __restrict__ attnO,
    const float* __restrict__ u, const u16* __restrict__ woT,
    const float* __restrict__ b_o, u16* __restrict__ outbl){
  __shared__ u16 atile[64*128];
  int b = blockIdx.y, lt = blockIdx.x;
  int tid = threadIdx.x;
  size_t rowbase = (size_t)(b*L_) + lt*64;
  for (int i = 0; i < 8; i++){
    int idx = tid + 256*i;
    int row = idx >> 5, d0 = (idx & 31)*4;
    size_t gofs = (rowbase + row)*128 + d0;
    float4 av = *(const float4*)&attnO[gofs];
    float4 uv = *(const float4*)&u[gofs];
    uint2 pk;
    pk.x = (u32)f2bf(av.x*uv.x) | ((u32)f2bf(av.y*uv.y) << 16);
    pk.y = (u32)f2bf(av.z*uv.z) | ((u32)f2bf(av.w*uv.w) << 16);
    int byte = (row*256 + d0*2) ^ ((row & 7) << 4);
    *(uint2*)((char*)atile + byte) = pk;
  }
  __syncthreads();
  int lane = tid & 63, wave = tid >> 6;
  int l15 = lane & 15, lg = lane >> 4;
  int n0 = wave*64;
  f32x4 zero = {0.f,0.f,0.f,0.f};
  f32x4 acc[4][4];
  for (int m=0;m<4;m++) for(int n=0;n<4;n++) acc[m][n]=zero;
  for (int ks = 0; ks < 4; ks++){
    bf16x8 a[4];
    #pragma unroll
    for (int m = 0; m < 4; m++){
      int row = m*16 + l15;
      int byte = (row*256 + ks*64 + lg*16) ^ ((row&7)<<4);
      a[m] = __builtin_bit_cast(bf16x8, *(const short8_t*)((char*)atile + byte));
    }
    #pragma unroll
    for (int n = 0; n < 4; n++){
      int col = n0 + n*16 + l15;
      bf16x8 bf = ld_bf8(&woT[col*128 + ks*32 + lg*8]);
      #pragma unroll
      for (int m = 0; m < 4; m++) acc[m][n] = mfma16(a[m], bf, acc[m][n]);
    }
  }
  for (int n = 0; n < 4; n++){
    int col = n0 + n*16 + l15;
    float bias = b_o[col];
    for (int m = 0; m < 4; m++)
      #pragma unroll
      for (int r = 0; r < 4; r++){
        size_t row = rowbase + m*16 + lg*4 + r;
        outbl[row*256 + col] = f2bf(acc[m][n][r] + bias);
      }
  }
}

// ---------------- K6: proj GEMM + residual/skip epilogue ----------------
__global__ __launch_bounds__(256) void gemm_proj(const u16* __restrict__ outbl,
    const u16* __restrict__ wp_bf, const float* __restrict__ b_p,
    const float* __restrict__ x, float* __restrict__ outp){
  __shared__ u16 atile[32*256];
  int b = blockIdx.y, lt = blockIdx.x; // 64 tiles of 32 rows
  int tid = threadIdx.x;
  size_t rowbase = (size_t)(b*L_) + lt*32;
  for (int i = 0; i < 4; i++){
    int chunk = tid + 256*i;
    int row = chunk >> 5, kc = chunk & 31;
    int byte = (row*512 + kc*16) ^ ((row & 7) << 4);
    *(short8_t*)((char*)atile + byte) = *(const short8_t*)&outbl[(rowbase + row)*256 + kc*8];
  }
  __syncthreads();
  int lane = tid & 63, wave = tid >> 6;
  int l15 = lane & 15, lg = lane >> 4;
  int n0 = wave*128;
  f32x4 zero = {0.f,0.f,0.f,0.f};
  f32x4 acc[2][8];
  for (int m=0;m<2;m++) for(int n=0;n<8;n++) acc[m][n]=zero;
  for (int ks = 0; ks < 8; ks++){
    bf16x8 a[2];
    #pragma unroll
    for (int m = 0; m < 2; m++){
      int row = m*16 + l15;
      int byte = (row*512 + ks*64 + lg*16) ^ ((row&7)<<4);
      a[m] = __builtin_bit_cast(bf16x8, *(const short8_t*)((char*)atile + byte));
    }
    #pragma unroll
    for (int n = 0; n < 8; n++){
      int col = n0 + n*16 + l15;
      bf16x8 bf = ld_bf8(&wp_bf[col*256 + ks*32 + lg*8]);
      #pragma unroll
      for (int m = 0; m < 2; m++) acc[m][n] = mfma16(a[m], bf, acc[m][n]);
    }
  }
  const float inv_s2 = 0.70710678118654752f;
  for (int n = 0; n < 8; n++){
    int o = n0 + n*16 + l15;
    float bias = b_p[o];
    for (int m = 0; m < 2; m++){
      int lofs = lt*32 + m*16 + lg*4;
      float4 v;
      v.x = acc[m][n][0] + bias; v.y = acc[m][n][1] + bias;
      v.z = acc[m][n][2] + bias; v.w = acc[m][n][3] + bias;
      if (o < 256){
        size_t xofs = ((size_t)b*256 + o)*L_ + lofs;
        float4 xv = *(const float4*)&x[xofs];
        v.x = (xv.x + v.x)*inv_s2; v.y = (xv.y + v.y)*inv_s2;
        v.z = (xv.z + v.z)*inv_s2; v.w = (xv.w + v.w)*inv_s2;
        *(float4*)&outp[xofs] = v;
      } else {
        size_t oofs = (size_t)B_*256*L_ + ((size_t)b*256 + (o-256))*L_ + lofs;
        *(float4*)&outp[oofs] = v;
      }
    }
  }
}

extern "C" void kernel_launch(void* const* d_in, const int* in_sizes, int n_in,
                              void* d_out, int out_size, void* d_ws, size_t ws_size,
                              hipStream_t stream){
  const float* x    = (const float*)d_in[0];
  const float* ln_g = (const float*)d_in[1];
  const float* ln_b = (const float*)d_in[2];
  const float* w_h  = (const float*)d_in[3];
  const float* b_h  = (const float*)d_in[4];
  const float* w_qk = (const float*)d_in[5];
  const float* b_qk = (const float*)d_in[6];
  const float* gamma= (const float*)d_in[7];
  const float* beta = (const float*)d_in[8];
  const float* w_o  = (const float*)d_in[9];
  const float* b_o  = (const float*)d_in[10];
  const float* w_p  = (const float*)d_in[11];
  const float* b_p  = (const float*)d_in[12];
  char* ws = (char*)d_ws;
  // layout (bytes):
  //  [0 .. 25165824)       hidz (dead after pointwise) -> then o_part [0..33554432), then outbl
  //  [25165824 .. 41943040) normed (dead after gemm_hid)
  //  [33554432 .. 34603008) ml (lives in dead normed region during attn)
  //  [41943040 ..) qm, km, vT, u, attnO, weights, rope tables
  u16*  hidz   = (u16*)(ws + 0);                 // 25,165,824
  u16*  o_part = (u16*)(ws + 0);                 // 33,554,432 (NSPLIT*BL*128 bf16; after pointwise)
  u16*  outbl  = (u16*)(ws + 0);                 // 16,777,216 (after combine)
  u16*  normed = (u16*)(ws + 25165824);          // 16,777,216
  float* ml    = (float*)(ws + 33554432);        //  1,048,576 (NSPLIT*BL*2 f32)
  u16*  qm     = (u16*)(ws + 41943040);          //  8,388,608
  u16*  km     = (u16*)(ws + 50331648);          //  8,388,608
  u16*  vT     = (u16*)(ws + 58720256);          //  8,388,608
  float* u     = (float*)(ws + 67108864);        // 16,777,216
  float* attnO = (float*)(ws + 83886080);        // 16,777,216
  u16*  wT1    = (u16*)(ws + 100663296);         //    196,608
  u16*  woT    = (u16*)(ws + 100663296 + 196608);//     65,536
  u16*  wp_bf  = (u16*)(ws + 100663296 + 262144);//    262,144
  float* bias384=(float*)(ws + 100663296 + 524288); //   2,048
  float* ctab  = (float*)(ws + 100663296 + 526336); // 524,288
  float* stab  = ctab + 2048*64;                    // 524,288
  float* outp  = (float*)d_out;

  prep_weights<<<dim3(512),dim3(256),0,stream>>>(w_h,w_qk,w_o,w_p,b_h,b_qk,wT1,woT,wp_bf,bias384);
  prep_rope<<<dim3(512),dim3(256),0,stream>>>(ctab,stab);
  ln_kernel<<<dim3(32,16),dim3(256),0,stream>>>(x,ln_g,ln_b,normed);
  gemm_hid<<<dim3(32,16),dim3(256),0,stream>>>(normed,wT1,bias384,hidz);
  pointwise_kernel<<<dim3(32,16),dim3(256),0,stream>>>(hidz,ctab,stab,gamma,beta,u,vT,qm,km);
  attn_split<<<dim3(32,16,NSPLIT),dim3(256),0,stream>>>(qm,km,vT,o_part,ml);
  attn_combine<<<dim3(BL_/8),dim3(256),0,stream>>>(o_part,ml,attnO);
  gemm_out<<<dim3(32,16),dim3(256),0,stream>>>(attnO,u,woT,b_o,outbl);
  gemm_proj<<<dim3(64,16),dim3(256),0,stream>>>(outbl,wp_bf,b_p,x,outp);
}

// Round 3
// 224.898 us; speedup vs baseline: 1.8550x; 1.8550x over previous
//
#include <hip/hip_runtime.h>
#include <hip/hip_bf16.h>
#include <math.h>

#define DEVINL __device__ __forceinline__

typedef __bf16 bf16x8 __attribute__((ext_vector_type(8)));
typedef short short8_t __attribute__((ext_vector_type(8)));
typedef float f32x4 __attribute__((ext_vector_type(4)));
typedef unsigned short u16;
typedef unsigned int u32;

#define B_ 16
#define L_ 2048
#define DIM_ 256
#define BL_ (B_*L_)

DEVINL u16 f2bf(float f){
  __hip_bfloat16 h = __float2bfloat16(f);
  return __builtin_bit_cast(u16, h);
}
DEVINL float bf2f(u16 u){
  __hip_bfloat16 h = __builtin_bit_cast(__hip_bfloat16, u);
  return __bfloat162float(h);
}
DEVINL float siluf(float x){ return x / (1.f + __expf(-x)); }
DEVINL f32x4 mfma16(bf16x8 a, bf16x8 b, f32x4 c){
  return __builtin_amdgcn_mfma_f32_16x16x32_bf16(a, b, c, 0, 0, 0);
}
DEVINL bf16x8 ld_bf8(const u16* p){
  return __builtin_bit_cast(bf16x8, *(const short8_t*)p);
}

// ---------------- P1: weight prep (transpose to [n][k] bf16) ----------------
__global__ __launch_bounds__(256) void prep_weights(
    const float* __restrict__ w_h, const float* __restrict__ w_qk,
    const float* __restrict__ w_o, const float* __restrict__ w_p,
    const float* __restrict__ b_h, const float* __restrict__ b_qk,
    u16* __restrict__ wT1, u16* __restrict__ woT,
    u16* __restrict__ wp_bf, float* __restrict__ bias384){
  int idx = blockIdx.x*256 + threadIdx.x;
  const int total = 384*256 + 256*128 + 512*256 + 384;
  for (; idx < total; idx += gridDim.x*256){
    int i = idx;
    if (i < 384*256){
      int n = i >> 8, k = i & 255;
      float v = (n < 256) ? w_h[k*256 + n] : w_qk[k*128 + (n-256)];
      wT1[i] = f2bf(v);
    } else if ((i -= 384*256) < 256*128){
      int n = i >> 7, k = i & 127;
      woT[i] = f2bf(w_o[k*256 + n]);
    } else if ((i -= 256*128) < 512*256){
      wp_bf[i] = f2bf(w_p[i]);
    } else {
      i -= 512*256;
      bias384[i] = (i < 256) ? b_h[i] : b_qk[i-256];
    }
  }
}

// ---------------- P2: rope tables ----------------
__global__ __launch_bounds__(256) void prep_rope(float* __restrict__ ctab, float* __restrict__ stab){
  int idx = blockIdx.x*256 + threadIdx.x; // 2048*64
  if (idx >= 2048*64) return;
  int l = idx >> 6, f = idx & 63;
  float inv = powf(10000.f, -(float)(2*f) * (1.f/128.f));
  float ang = (float)l * inv;
  ctab[idx] = cosf(ang);
  stab[idx] = sinf(ang);
}

// ---------------- K1: layernorm (b,c,l)->bf16 (b,l,c) ----------------
__global__ __launch_bounds__(256) void ln_kernel(const float* __restrict__ x,
    const float* __restrict__ ln_g, const float* __restrict__ ln_b,
    u16* __restrict__ normed){
  __shared__ float xs[256][65];
  __shared__ float redsum[4][64], redsq[4][64];
  __shared__ float mu_s[64], rs_s[64];
  int b = blockIdx.y, lt = blockIdx.x;
  int tid = threadIdx.x;
  int tx = tid & 63, ty = tid >> 6;
  size_t xbase = (size_t)b*DIM_*L_ + (size_t)lt*64;
  float s = 0.f, s2 = 0.f;
  for (int c = ty; c < 256; c += 4){
    float v = x[xbase + (size_t)c*L_ + tx];
    xs[c][tx] = v;
    s += v; s2 += v*v;
  }
  redsum[ty][tx] = s; redsq[ty][tx] = s2;
  __syncthreads();
  if (ty == 0){
    float ss = redsum[0][tx]+redsum[1][tx]+redsum[2][tx]+redsum[3][tx];
    float qq = redsq[0][tx]+redsq[1][tx]+redsq[2][tx]+redsq[3][tx];
    float mu = ss * (1.f/256.f);
    float var = qq * (1.f/256.f) - mu*mu;
    mu_s[tx] = mu;
    rs_s[tx] = rsqrtf(var + 1e-5f);
  }
  __syncthreads();
  for (int i = 0; i < 8; i++){
    int chunk = tid + 256*i;
    int l = chunk >> 5, c0 = (chunk & 31) * 8;
    float mu = mu_s[l], rs = rs_s[l];
    short8_t outv;
    #pragma unroll
    for (int j = 0; j < 8; j++){
      int c = c0 + j;
      float v = (xs[c][l] - mu) * rs * ln_g[c] + ln_b[c];
      outv[j] = (short)f2bf(v);
    }
    *(short8_t*)&normed[((size_t)(b*L_) + lt*64 + l)*256 + c0] = outv;
  }
}

// ---------------- K2: GEMM1 normed @ [w_h | w_qk] + bias -> hidz bf16 (b,l,384)
__global__ __launch_bounds__(256) void gemm_hid(const u16* __restrict__ normed,
    const u16* __restrict__ wT1, const float* __restrict__ bias384,
    u16* __restrict__ hidz){
  __shared__ u16 atile[64*256];
  int b = blockIdx.y, lt = blockIdx.x;
  int tid = threadIdx.x;
  for (int i = 0; i < 8; i++){
    int chunk = tid + 256*i;
    int row = chunk >> 5, kc = chunk & 31;
    int byte = (row*512 + kc*16) ^ ((row & 7) << 4);
    *(short8_t*)((char*)atile + byte) =
        *(const short8_t*)&normed[((size_t)(b*L_) + lt*64 + row)*256 + kc*8];
  }
  __syncthreads();
  int lane = tid & 63, wave = tid >> 6;
  int l15 = lane & 15, lg = lane >> 4;
  int n0 = wave * 96;
  f32x4 zero = {0.f,0.f,0.f,0.f};
  f32x4 acc[4][6];
  for (int m=0;m<4;m++) for (int n=0;n<6;n++) acc[m][n]=zero;
  for (int ks = 0; ks < 8; ks++){
    bf16x8 a[4];
    #pragma unroll
    for (int m = 0; m < 4; m++){
      int row = m*16 + l15;
      int byte = (row*512 + ks*64 + lg*16) ^ ((row & 7) << 4);
      a[m] = __builtin_bit_cast(bf16x8, *(const short8_t*)((char*)atile + byte));
    }
    #pragma unroll
    for (int n = 0; n < 6; n++){
      int col = n0 + n*16 + l15;
      bf16x8 bfrag = ld_bf8(&wT1[col*256 + ks*32 + lg*8]);
      #pragma unroll
      for (int m = 0; m < 4; m++)
        acc[m][n] = mfma16(a[m], bfrag, acc[m][n]);
    }
  }
  for (int n = 0; n < 6; n++){
    int col = n0 + n*16 + l15;
    float bias = bias384[col];
    for (int m = 0; m < 4; m++)
      #pragma unroll
      for (int r = 0; r < 4; r++){
        size_t row = (size_t)(b*L_) + lt*64 + m*16 + lg*4 + r;
        hidz[row*384 + col] = f2bf(acc[m][n][r] + bias);
      }
  }
}

// ---------------- K3: pointwise silu / rope -> u, vT, q (pre-scaled 1/L), k ----
__global__ __launch_bounds__(256) void pointwise_kernel(const u16* __restrict__ hidz,
    const float* __restrict__ ctab, const float* __restrict__ stab,
    const float* __restrict__ gamma, const float* __restrict__ beta,
    float* __restrict__ u, u16* __restrict__ vT,
    u16* __restrict__ qm, u16* __restrict__ km){
  __shared__ u16 vs[64][130];
  int b = blockIdx.y, lt = blockIdx.x;
  int tid = threadIdx.x;
  size_t rowbase = (size_t)(b*L_) + lt*64;
  for (int i = 0; i < 32; i++){
    int idx = tid + 256*i;
    int l = idx >> 7, d = idx & 127;
    size_t row = rowbase + l;
    u[row*128 + d] = siluf(bf2f(hidz[row*384 + 128 + d]));
    vs[l][d] = hidz[row*384 + d];
  }
  __syncthreads();
  for (int i = 0; i < 4; i++){
    int chunk = tid + 256*i;
    int d = chunk >> 3, lc = (chunk & 7)*8;
    short8_t vv;
    #pragma unroll
    for (int j = 0; j < 8; j++)
      vv[j] = (short)f2bf(siluf(bf2f(vs[lc + j][d])));
    *(short8_t*)&vT[((size_t)b*128 + d)*2048 + lt*64 + lc] = vv;
  }
  const float inv_L = 1.f/(float)L_;
  for (int i = 0; i < 16; i++){
    int idx = tid + 256*i;
    int l = idx >> 6, f = idx & 63;
    size_t row = rowbase + l;
    u32 zz = *(const u32*)&hidz[row*384 + 256 + 2*f];
    float z1 = siluf(bf2f((u16)(zz & 0xffffu)));
    float z2 = siluf(bf2f((u16)(zz >> 16)));
    int gl = lt*64 + l;
    float c = ctab[gl*64 + f], s = stab[gl*64 + f];
    float q1 = z1*gamma[2*f]   + beta[2*f];
    float q2 = z2*gamma[2*f+1] + beta[2*f+1];
    u32 qp = (u32)f2bf((q1*c - q2*s)*inv_L) | ((u32)f2bf((q1*s + q2*c)*inv_L) << 16);
    *(u32*)&qm[row*128 + 2*f] = qp;
    float k1 = z1*gamma[128 + 2*f]   + beta[128 + 2*f];
    float k2 = z2*gamma[128 + 2*f+1] + beta[128 + 2*f+1];
    u32 kp = (u32)f2bf(k1*c - k2*s) | ((u32)f2bf(k1*s + k2*c) << 16);
    *(u32*)&km[row*128 + 2*f] = kp;
  }
}

// ---------------- K4: flash attention, LDS-staged KV tiles ----------------
// block = 4 waves, 64 q-rows; KV tile = 64 rows. K/V staged once per block
// into XOR-swizzled LDS; next tile's global loads issued before compute.
__global__ __launch_bounds__(256) void attn_kernel(const u16* __restrict__ qm,
    const u16* __restrict__ km, const u16* __restrict__ vT,
    float* __restrict__ attnO){
  __shared__ u16 Klds[64*128];    // [kv=64][d=128], row 256B, swz ^((row&7)<<4)
  __shared__ u16 Vlds[128*64];    // [d=128][kv=64], row 128B, swz ^((row&7)<<4)
  __shared__ u16 pbuf[4][16*64];  // per-wave P: [qrow=16][kv=64], row 128B, swz
  int b = blockIdx.y, qt = blockIdx.x;
  int tid = threadIdx.x;
  int lane = tid & 63, wave = tid >> 6;
  int l15 = lane & 15, lg = lane >> 4;
  int qrow0 = qt*64 + wave*16;
  size_t qbase = ((size_t)(b*L_) + qrow0 + l15) * 128;
  bf16x8 qf[4];
  #pragma unroll
  for (int ks = 0; ks < 4; ks++)
    qf[ks] = ld_bf8(&qm[qbase + ks*32 + lg*8]);
  f32x4 zero = {0.f,0.f,0.f,0.f};
  f32x4 o[8];
  #pragma unroll
  for (int n = 0; n < 8; n++) o[n] = zero;
  float m[4], lsum[4];
  #pragma unroll
  for (int r = 0; r < 4; r++){ m[r] = -1e30f; lsum[r] = 0.f; }
  const u16* kb = km + (size_t)(b*L_)*128;
  const u16* vb = vT + (size_t)b*128*2048;
  // staging addresses: K pass p covers rows p*16+(tid>>4), 16B col (tid&15)
  int krow = tid >> 4, kcol = tid & 15;
  int vd   = tid >> 3, vcol = tid & 7;
  const u16* kg = kb + (size_t)krow*128 + (size_t)kcol*8;
  const u16* vg = vb + (size_t)vd*2048 + (size_t)vcol*8;
  char* Kb = (char*)Klds;
  char* Vb = (char*)Vlds;
  char* Pb = (char*)pbuf + wave*2048;
  int kofs = (krow*256 + kcol*16) ^ ((krow & 7) << 4);  // +p*4096 (p*16 keeps row&7)
  int vofs = (vd*128  + vcol*16) ^ ((vd  & 7) << 4);    // +p*4096 (p*32 keeps row&7)
  short8_t kr[4], vr[4];
  #pragma unroll
  for (int p = 0; p < 4; p++){
    kr[p] = *(const short8_t*)(kg + (size_t)(p*16)*128);
    vr[p] = *(const short8_t*)(vg + (size_t)p*32*2048);
  }
  #pragma unroll 1
  for (int jt = 0; jt < 32; ++jt){
    __syncthreads();               // previous compute done: LDS safe to overwrite
    #pragma unroll
    for (int p = 0; p < 4; p++){
      *(short8_t*)(Kb + kofs + p*4096) = kr[p];
      *(short8_t*)(Vb + vofs + p*4096) = vr[p];
    }
    __syncthreads();               // tile visible
    if (jt < 31){                  // issue next tile's loads early (hide under compute)
      int j0 = (jt+1)*64;
      #pragma unroll
      for (int p = 0; p < 4; p++){
        kr[p] = *(const short8_t*)(kg + (size_t)(j0 + p*16)*128);
        vr[p] = *(const short8_t*)(vg + (size_t)j0 + (size_t)p*32*2048);
      }
    }
    // ---- QK^T on LDS tile: S[16 q][64 kv] ----
    f32x4 s[4];
    #pragma unroll
    for (int jj = 0; jj < 4; jj++){
      s[jj] = zero;
      #pragma unroll
      for (int ks = 0; ks < 4; ks++){
        int row = jj*16 + l15;
        int byte = (row*256 + ks*64 + lg*16) ^ ((row & 7) << 4);
        bf16x8 kf = __builtin_bit_cast(bf16x8, *(const short8_t*)(Kb + byte));
        s[jj] = mfma16(qf[ks], kf, s[jj]);
      }
    }
    // ---- online softmax (row = lg*4+r, cols = jj*16+l15) ----
    float corr[4];
    #pragma unroll
    for (int r = 0; r < 4; r++){
      float t = fmaxf(fmaxf(s[0][r], s[1][r]), fmaxf(s[2][r], s[3][r]));
      t = fmaxf(t, __shfl_xor(t, 1));
      t = fmaxf(t, __shfl_xor(t, 2));
      t = fmaxf(t, __shfl_xor(t, 4));
      t = fmaxf(t, __shfl_xor(t, 8));
      float mn = fmaxf(m[r], t);
      float cr = __expf(m[r] - mn);
      corr[r] = cr;
      m[r] = mn;
      int rw = lg*4 + r;
      float psum = 0.f;
      #pragma unroll
      for (int jj = 0; jj < 4; jj++){
        float p = __expf(s[jj][r] - mn);
        psum += p;
        int cbyte = rw*128 + (((jj*16 + l15)*2) ^ ((rw & 7) << 4));
        *(u16*)(Pb + cbyte) = f2bf(p);
      }
      lsum[r] = lsum[r]*cr + psum;   // per-lane partial; reduced after loop
    }
    #pragma unroll
    for (int n = 0; n < 8; n++)
      #pragma unroll
      for (int r = 0; r < 4; r++)
        o[n][r] *= corr[r];
    // ---- PV: O[16 q][128 d] += P @ V ----
    bf16x8 pa[2];
    #pragma unroll
    for (int half = 0; half < 2; half++){
      int pbyte = l15*128 + ((half*64 + lg*16) ^ ((l15 & 7) << 4));
      pa[half] = __builtin_bit_cast(bf16x8, *(const short8_t*)(Pb + pbyte));
    }
    #pragma unroll
    for (int n = 0; n < 8; n++){
      #pragma unroll
      for (int half = 0; half < 2; half++){
        int vrow = n*16 + l15;
        int byte = (vrow*128 + half*64 + lg*16) ^ ((vrow & 7) << 4);
        bf16x8 vf = __builtin_bit_cast(bf16x8, *(const short8_t*)(Vb + byte));
        o[n] = mfma16(pa[half], vf, o[n]);
      }
    }
  }
  // finish: reduce per-lane lsum partials across the 16 kv-columns
  #pragma unroll
  for (int r = 0; r < 4; r++){
    float ls = lsum[r];
    ls += __shfl_xor(ls, 1);
    ls += __shfl_xor(ls, 2);
    ls += __shfl_xor(ls, 4);
    ls += __shfl_xor(ls, 8);
    lsum[r] = ls;
  }
  #pragma unroll
  for (int r = 0; r < 4; r++){
    float inv = 1.f / lsum[r];
    size_t row = (size_t)(b*L_) + qrow0 + lg*4 + r;
    #pragma unroll
    for (int n = 0; n < 8; n++)
      attnO[row*128 + n*16 + l15] = o[n][r] * inv;
  }
}

// ---------------- K5: (u*V) @ w_o + b_o -> outbl bf16 (b,l,256) ----------------
__global__ __launch_bounds__(256) void gemm_out(const float* __restrict__ attnO,
    const float* __restrict__ u, const u16* __restrict__ woT,
    const float* __restrict__ b_o, u16* __restrict__ outbl){
  __shared__ u16 atile[64*128];
  int b = blockIdx.y, lt = blockIdx.x;
  int tid = threadIdx.x;
  size_t rowbase = (size_t)(b*L_) + lt*64;
  for (int i = 0; i < 8; i++){
    int idx = tid + 256*i;
    int row = idx >> 5, d0 = (idx & 31)*4;
    size_t gofs = (rowbase + row)*128 + d0;
    float4 av = *(const float4*)&attnO[gofs];
    float4 uv = *(const float4*)&u[gofs];
    uint2 pk;
    pk.x = (u32)f2bf(av.x*uv.x) | ((u32)f2bf(av.y*uv.y) << 16);
    pk.y = (u32)f2bf(av.z*uv.z) | ((u32)f2bf(av.w*uv.w) << 16);
    int byte = (row*256 + d0*2) ^ ((row & 7) << 4);
    *(uint2*)((char*)atile + byte) = pk;
  }
  __syncthreads();
  int lane = tid & 63, wave = tid >> 6;
  int l15 = lane & 15, lg = lane >> 4;
  int n0 = wave*64;
  f32x4 zero = {0.f,0.f,0.f,0.f};
  f32x4 acc[4][4];
  for (int m=0;m<4;m++) for(int n=0;n<4;n++) acc[m][n]=zero;
  for (int ks = 0; ks < 4; ks++){
    bf16x8 a[4];
    #pragma unroll
    for (int m = 0; m < 4; m++){
      int row = m*16 + l15;
      int byte = (row*256 + ks*64 + lg*16) ^ ((row&7)<<4);
      a[m] = __builtin_bit_cast(bf16x8, *(const short8_t*)((char*)atile + byte));
    }
    #pragma unroll
    for (int n = 0; n < 4; n++){
      int col = n0 + n*16 + l15;
      bf16x8 bf = ld_bf8(&woT[col*128 + ks*32 + lg*8]);
      #pragma unroll
      for (int m = 0; m < 4; m++) acc[m][n] = mfma16(a[m], bf, acc[m][n]);
    }
  }
  for (int n = 0; n < 4; n++){
    int col = n0 + n*16 + l15;
    float bias = b_o[col];
    for (int m = 0; m < 4; m++)
      #pragma unroll
      for (int r = 0; r < 4; r++){
        size_t row = rowbase + m*16 + lg*4 + r;
        outbl[row*256 + col] = f2bf(acc[m][n][r] + bias);
      }
  }
}

// ---------------- K6: proj GEMM + residual/skip epilogue ----------------
__global__ __launch_bounds__(256) void gemm_proj(const u16* __restrict__ outbl,
    const u16* __restrict__ wp_bf, const float* __restrict__ b_p,
    const float* __restrict__ x, float* __restrict__ outp){
  __shared__ u16 atile[32*256];
  int b = blockIdx.y, lt = blockIdx.x; // 64 tiles of 32 rows
  int tid = threadIdx.x;
  size_t rowbase = (size_t)(b*L_) + lt*32;
  for (int i = 0; i < 4; i++){
    int chunk = tid + 256*i;
    int row = chunk >> 5, kc = chunk & 31;
    int byte = (row*512 + kc*16) ^ ((row & 7) << 4);
    *(short8_t*)((char*)atile + byte) = *(const short8_t*)&outbl[(rowbase + row)*256 + kc*8];
  }
  __syncthreads();
  int lane = tid & 63, wave = tid >> 6;
  int l15 = lane & 15, lg = lane >> 4;
  int n0 = wave*128;
  f32x4 zero = {0.f,0.f,0.f,0.f};
  f32x4 acc[2][8];
  for (int m=0;m<2;m++) for(int n=0;n<8;n++) acc[m][n]=zero;
  for (int ks = 0; ks < 8; ks++){
    bf16x8 a[2];
    #pragma unroll
    for (int m = 0; m < 2; m++){
      int row = m*16 + l15;
      int byte = (row*512 + ks*64 + lg*16) ^ ((row&7)<<4);
      a[m] = __builtin_bit_cast(bf16x8, *(const short8_t*)((char*)atile + byte));
    }
    #pragma unroll
    for (int n = 0; n < 8; n++){
      int col = n0 + n*16 + l15;
      bf16x8 bf = ld_bf8(&wp_bf[col*256 + ks*32 + lg*8]);
      #pragma unroll
      for (int m = 0; m < 2; m++) acc[m][n] = mfma16(a[m], bf, acc[m][n]);
    }
  }
  const float inv_s2 = 0.70710678118654752f;
  for (int n = 0; n < 8; n++){
    int o = n0 + n*16 + l15;
    float bias = b_p[o];
    for (int m = 0; m < 2; m++){
      int lofs = lt*32 + m*16 + lg*4;
      float4 v;
      v.x = acc[m][n][0] + bias; v.y = acc[m][n][1] + bias;
      v.z = acc[m][n][2] + bias; v.w = acc[m][n][3] + bias;
      if (o < 256){
        size_t xofs = ((size_t)b*256 + o)*L_ + lofs;
        float4 xv = *(const float4*)&x[xofs];
        v.x = (xv.x + v.x)*inv_s2; v.y = (xv.y + v.y)*inv_s2;
        v.z = (xv.z + v.z)*inv_s2; v.w = (xv.w + v.w)*inv_s2;
        *(float4*)&outp[xofs] = v;
      } else {
        size_t oofs = (size_t)B_*256*L_ + ((size_t)b*256 + (o-256))*L_ + lofs;
        *(float4*)&outp[oofs] = v;
      }
    }
  }
}

extern "C" void kernel_launch(void* const* d_in, const int* in_sizes, int n_in,
                              void* d_out, int out_size, void* d_ws, size_t ws_size,
                              hipStream_t stream){
  const float* x    = (const float*)d_in[0];
  const float* ln_g = (const float*)d_in[1];
  const float* ln_b = (const float*)d_in[2];
  const float* w_h  = (const float*)d_in[3];
  const float* b_h  = (const float*)d_in[4];
  const float* w_qk = (const float*)d_in[5];
  const float* b_qk = (const float*)d_in[6];
  const float* gamma= (const float*)d_in[7];
  const float* beta = (const float*)d_in[8];
  const float* w_o  = (const float*)d_in[9];
  const float* b_o  = (const float*)d_in[10];
  const float* w_p  = (const float*)d_in[11];
  const float* b_p  = (const float*)d_in[12];
  char* ws = (char*)d_ws;
  u16*  hidz   = (u16*)(ws + 0);                 // 25,165,824 (dead after pointwise)
  u16*  outbl  = (u16*)(ws + 0);                 // 16,777,216 (reuse)
  u16*  normed = (u16*)(ws + 25165824);          // 16,777,216
  u16*  qm     = (u16*)(ws + 41943040);          //  8,388,608
  u16*  km     = (u16*)(ws + 50331648);          //  8,388,608
  u16*  vT     = (u16*)(ws + 58720256);          //  8,388,608
  float* u     = (float*)(ws + 67108864);        // 16,777,216
  float* attnO = (float*)(ws + 83886080);        // 16,777,216
  u16*  wT1    = (u16*)(ws + 100663296);         //    196,608
  u16*  woT    = (u16*)(ws + 100663296 + 196608);//     65,536
  u16*  wp_bf  = (u16*)(ws + 100663296 + 262144);//    262,144
  float* bias384=(float*)(ws + 100663296 + 524288); //   2,048
  float* ctab  = (float*)(ws + 100663296 + 526336); // 524,288
  float* stab  = ctab + 2048*64;                    // 524,288
  float* outp  = (float*)d_out;

  prep_weights<<<dim3(512),dim3(256),0,stream>>>(w_h,w_qk,w_o,w_p,b_h,b_qk,wT1,woT,wp_bf,bias384);
  prep_rope<<<dim3(512),dim3(256),0,stream>>>(ctab,stab);
  ln_kernel<<<dim3(32,16),dim3(256),0,stream>>>(x,ln_g,ln_b,normed);
  gemm_hid<<<dim3(32,16),dim3(256),0,stream>>>(normed,wT1,bias384,hidz);
  pointwise_kernel<<<dim3(32,16),dim3(256),0,stream>>>(hidz,ctab,stab,gamma,beta,u,vT,qm,km);
  attn_kernel<<<dim3(32,16),dim3(256),0,stream>>>(qm,km,vT,attnO);
  gemm_out<<<dim3(32,16),dim3(256),0,stream>>>(attnO,u,woT,b_o,outbl);
  gemm_proj<<<dim3(64,16),dim3(256),0,stream>>>(outbl,wp_bf,b_p,x,outp);
}

// Round 4
// 198.844 us; speedup vs baseline: 2.0980x; 1.1310x over previous
//
#include <hip/hip_runtime.h>
#include <hip/hip_bf16.h>
#include <math.h>

#define DEVINL __device__ __forceinline__

typedef __bf16 bf16x8 __attribute__((ext_vector_type(8)));
typedef short short8_t __attribute__((ext_vector_type(8)));
typedef float f32x4 __attribute__((ext_vector_type(4)));
typedef float f32x16 __attribute__((ext_vector_type(16)));
typedef unsigned short u16;
typedef unsigned int u32;

#define B_ 16
#define L_ 2048
#define DIM_ 256
#define BL_ (B_*L_)
#define NSPLIT 2

DEVINL u16 f2bf(float f){
  __hip_bfloat16 h = __float2bfloat16(f);
  return __builtin_bit_cast(u16, h);
}
DEVINL float bf2f(u16 u){
  __hip_bfloat16 h = __builtin_bit_cast(__hip_bfloat16, u);
  return __bfloat162float(h);
}
DEVINL float siluf(float x){ return x / (1.f + __expf(-x)); }
DEVINL f32x4 mfma16(bf16x8 a, bf16x8 b, f32x4 c){
  return __builtin_amdgcn_mfma_f32_16x16x32_bf16(a, b, c, 0, 0, 0);
}
DEVINL f32x16 mfma32(bf16x8 a, bf16x8 b, f32x16 c){
  return __builtin_amdgcn_mfma_f32_32x32x16_bf16(a, b, c, 0, 0, 0);
}
DEVINL bf16x8 ld_bf8(const u16* p){
  return __builtin_bit_cast(bf16x8, *(const short8_t*)p);
}
DEVINL bf16x8 ldf(const char* p){
  return __builtin_bit_cast(bf16x8, *(const short8_t*)p);
}
DEVINL u32 cvtpk(float lo, float hi_){
  u32 r;
  asm("v_cvt_pk_bf16_f32 %0, %1, %2" : "=v"(r) : "v"(lo), "v"(hi_));
  return r;
}
DEVINL bf16x8 mkfrag(u32 a, u32 b, u32 c, u32 d){
  union { u32 w[4]; bf16x8 v; } u_;
  u_.w[0]=a; u_.w[1]=b; u_.w[2]=c; u_.w[3]=d;
  return u_.v;
}
DEVINL f32x16 zero16(){
  f32x16 v;
  #pragma unroll
  for (int i = 0; i < 16; i++) v[i] = 0.f;
  return v;
}

// ---------------- P1: weight prep (transpose to [n][k] bf16) ----------------
__global__ __launch_bounds__(256) void prep_weights(
    const float* __restrict__ w_h, const float* __restrict__ w_qk,
    const float* __restrict__ w_o, const float* __restrict__ w_p,
    const float* __restrict__ b_h, const float* __restrict__ b_qk,
    u16* __restrict__ wT1, u16* __restrict__ woT,
    u16* __restrict__ wp_bf, float* __restrict__ bias384){
  int idx = blockIdx.x*256 + threadIdx.x;
  const int total = 384*256 + 256*128 + 512*256 + 384;
  for (; idx < total; idx += gridDim.x*256){
    int i = idx;
    if (i < 384*256){
      int n = i >> 8, k = i & 255;
      float v = (n < 256) ? w_h[k*256 + n] : w_qk[k*128 + (n-256)];
      wT1[i] = f2bf(v);
    } else if ((i -= 384*256) < 256*128){
      int n = i >> 7, k = i & 127;
      woT[i] = f2bf(w_o[k*256 + n]);
    } else if ((i -= 256*128) < 512*256){
      wp_bf[i] = f2bf(w_p[i]);
    } else {
      i -= 512*256;
      bias384[i] = (i < 256) ? b_h[i] : b_qk[i-256];
    }
  }
}

// ---------------- P2: rope tables ----------------
__global__ __launch_bounds__(256) void prep_rope(float* __restrict__ ctab, float* __restrict__ stab){
  int idx = blockIdx.x*256 + threadIdx.x; // 2048*64
  if (idx >= 2048*64) return;
  int l = idx >> 6, f = idx & 63;
  float inv = powf(10000.f, -(float)(2*f) * (1.f/128.f));
  float ang = (float)l * inv;
  ctab[idx] = cosf(ang);
  stab[idx] = sinf(ang);
}

// ---------------- K1: layernorm (b,c,l)->bf16 (b,l,c) ----------------
__global__ __launch_bounds__(256) void ln_kernel(const float* __restrict__ x,
    const float* __restrict__ ln_g, const float* __restrict__ ln_b,
    u16* __restrict__ normed){
  __shared__ float xs[256][65];
  __shared__ float redsum[4][64], redsq[4][64];
  __shared__ float mu_s[64], rs_s[64];
  int b = blockIdx.y, lt = blockIdx.x;
  int tid = threadIdx.x;
  int tx = tid & 63, ty = tid >> 6;
  size_t xbase = (size_t)b*DIM_*L_ + (size_t)lt*64;
  float s = 0.f, s2 = 0.f;
  for (int c = ty; c < 256; c += 4){
    float v = x[xbase + (size_t)c*L_ + tx];
    xs[c][tx] = v;
    s += v; s2 += v*v;
  }
  redsum[ty][tx] = s; redsq[ty][tx] = s2;
  __syncthreads();
  if (ty == 0){
    float ss = redsum[0][tx]+redsum[1][tx]+redsum[2][tx]+redsum[3][tx];
    float qq = redsq[0][tx]+redsq[1][tx]+redsq[2][tx]+redsq[3][tx];
    float mu = ss * (1.f/256.f);
    float var = qq * (1.f/256.f) - mu*mu;
    mu_s[tx] = mu;
    rs_s[tx] = rsqrtf(var + 1e-5f);
  }
  __syncthreads();
  for (int i = 0; i < 8; i++){
    int chunk = tid + 256*i;
    int l = chunk >> 5, c0 = (chunk & 31) * 8;
    float mu = mu_s[l], rs = rs_s[l];
    short8_t outv;
    #pragma unroll
    for (int j = 0; j < 8; j++){
      int c = c0 + j;
      float v = (xs[c][l] - mu) * rs * ln_g[c] + ln_b[c];
      outv[j] = (short)f2bf(v);
    }
    *(short8_t*)&normed[((size_t)(b*L_) + lt*64 + l)*256 + c0] = outv;
  }
}

// ---------------- K2: GEMM1 normed @ [w_h | w_qk] + bias -> hidz bf16 (b,l,384)
__global__ __launch_bounds__(256) void gemm_hid(const u16* __restrict__ normed,
    const u16* __restrict__ wT1, const float* __restrict__ bias384,
    u16* __restrict__ hidz){
  __shared__ u16 atile[64*256];
  int b = blockIdx.y, lt = blockIdx.x;
  int tid = threadIdx.x;
  for (int i = 0; i < 8; i++){
    int chunk = tid + 256*i;
    int row = chunk >> 5, kc = chunk & 31;
    int byte = (row*512 + kc*16) ^ ((row & 7) << 4);
    *(short8_t*)((char*)atile + byte) =
        *(const short8_t*)&normed[((size_t)(b*L_) + lt*64 + row)*256 + kc*8];
  }
  __syncthreads();
  int lane = tid & 63, wave = tid >> 6;
  int l15 = lane & 15, lg = lane >> 4;
  int n0 = wave * 96;
  f32x4 zero = {0.f,0.f,0.f,0.f};
  f32x4 acc[4][6];
  for (int m=0;m<4;m++) for (int n=0;n<6;n++) acc[m][n]=zero;
  for (int ks = 0; ks < 8; ks++){
    bf16x8 a[4];
    #pragma unroll
    for (int m = 0; m < 4; m++){
      int row = m*16 + l15;
      int byte = (row*512 + ks*64 + lg*16) ^ ((row & 7) << 4);
      a[m] = __builtin_bit_cast(bf16x8, *(const short8_t*)((char*)atile + byte));
    }
    #pragma unroll
    for (int n = 0; n < 6; n++){
      int col = n0 + n*16 + l15;
      bf16x8 bfrag = ld_bf8(&wT1[col*256 + ks*32 + lg*8]);
      #pragma unroll
      for (int m = 0; m < 4; m++)
        acc[m][n] = mfma16(a[m], bfrag, acc[m][n]);
    }
  }
  for (int n = 0; n < 6; n++){
    int col = n0 + n*16 + l15;
    float bias = bias384[col];
    for (int m = 0; m < 4; m++)
      #pragma unroll
      for (int r = 0; r < 4; r++){
        size_t row = (size_t)(b*L_) + lt*64 + m*16 + lg*4 + r;
        hidz[row*384 + col] = f2bf(acc[m][n][r] + bias);
      }
  }
}

// ---------------- K3: pointwise silu / rope -> u, vT, q (pre-scaled 1/L), k ----
__global__ __launch_bounds__(256) void pointwise_kernel(const u16* __restrict__ hidz,
    const float* __restrict__ ctab, const float* __restrict__ stab,
    const float* __restrict__ gamma, const float* __restrict__ beta,
    float* __restrict__ u, u16* __restrict__ vT,
    u16* __restrict__ qm, u16* __restrict__ km){
  __shared__ u16 vs[64][130];
  int b = blockIdx.y, lt = blockIdx.x;
  int tid = threadIdx.x;
  size_t rowbase = (size_t)(b*L_) + lt*64;
  for (int i = 0; i < 32; i++){
    int idx = tid + 256*i;
    int l = idx >> 7, d = idx & 127;
    size_t row = rowbase + l;
    u[row*128 + d] = siluf(bf2f(hidz[row*384 + 128 + d]));
    vs[l][d] = hidz[row*384 + d];
  }
  __syncthreads();
  for (int i = 0; i < 4; i++){
    int chunk = tid + 256*i;
    int d = chunk >> 3, lc = (chunk & 7)*8;
    short8_t vv;
    #pragma unroll
    for (int j = 0; j < 8; j++)
      vv[j] = (short)f2bf(siluf(bf2f(vs[lc + j][d])));
    *(short8_t*)&vT[((size_t)b*128 + d)*2048 + lt*64 + lc] = vv;
  }
  const float inv_L = 1.f/(float)L_;
  for (int i = 0; i < 16; i++){
    int idx = tid + 256*i;
    int l = idx >> 6, f = idx & 63;
    size_t row = rowbase + l;
    u32 zz = *(const u32*)&hidz[row*384 + 256 + 2*f];
    float z1 = siluf(bf2f((u16)(zz & 0xffffu)));
    float z2 = siluf(bf2f((u16)(zz >> 16)));
    int gl = lt*64 + l;
    float c = ctab[gl*64 + f], s = stab[gl*64 + f];
    float q1 = z1*gamma[2*f]   + beta[2*f];
    float q2 = z2*gamma[2*f+1] + beta[2*f+1];
    u32 qp = (u32)f2bf((q1*c - q2*s)*inv_L) | ((u32)f2bf((q1*s + q2*c)*inv_L) << 16);
    *(u32*)&qm[row*128 + 2*f] = qp;
    float k1 = z1*gamma[128 + 2*f]   + beta[128 + 2*f];
    float k2 = z2*gamma[128 + 2*f+1] + beta[128 + 2*f+1];
    u32 kp = (u32)f2bf(k1*c - k2*s) | ((u32)f2bf(k1*s + k2*c) << 16);
    *(u32*)&km[row*128 + 2*f] = kp;
  }
}

// ---------------- K4: flash attention, 32x32 swapped-operand, split-KV --------
// wave = 32 q-rows; block = 4 waves (128 q); KV chunk = 1024 (z of 2), tiles of 64.
// QK^T swapped: S^T = mfma(K, Q): lane holds P-row for q = lane&31.
// PV swapped:   O^T = mfma(V^T, P^T): col = q = lane&31 (lane-local softmax state).
__global__ __launch_bounds__(256, 2) void attn_split(const u16* __restrict__ qm,
    const u16* __restrict__ km, const u16* __restrict__ vT,
    u16* __restrict__ o_part, float* __restrict__ ml){
  __shared__ u16 Klds[64*128];    // [kv=64][d=128] rows 256B, swz ^((row&15)<<4)
  __shared__ u16 Vlds[128*128];   // [d=128][kv 64 used] rows padded to 256B, same swz
  int b = blockIdx.y, qt = blockIdx.x, z = blockIdx.z;
  int tid = threadIdx.x;
  int lane = tid & 63, wave = tid >> 6;
  int q31 = lane & 31, hi = lane >> 5;
  int hi16 = hi << 4;
  int qrow0 = qt*128 + wave*32;
  // Q preload: B-frag B^T[col=q][k=d] = Q[q][s*16 + hi*8 + 0..7]
  size_t qbase = ((size_t)(b*L_) + qrow0 + q31)*128 + hi*8;
  bf16x8 qf[8];
  #pragma unroll
  for (int s = 0; s < 8; s++)
    qf[s] = ld_bf8(&qm[qbase + s*16]);
  // staging addressing
  int krow = tid >> 4, kcol = tid & 15;   // 16 kv-rows/pass, 16B cols
  int vd   = tid >> 3, vcol = tid & 7;    // 32 d-rows/pass, 16B cols
  const u16* kg = km + ((size_t)(b*L_) + z*1024 + krow)*128 + kcol*8;
  const u16* vg = vT + ((size_t)b*128 + vd)*2048 + (size_t)z*1024 + vcol*8;
  char* Kw = (char*)Klds + krow*256 + ((kcol*16) ^ ((krow & 15) << 4));
  char* Vw = (char*)Vlds + vd*256  + ((vcol*16) ^ ((vd  & 15) << 4));
  short8_t kr[4], vr[4];
  #pragma unroll
  for (int p = 0; p < 4; p++){
    kr[p] = *(const short8_t*)(kg + (size_t)p*16*128);
    vr[p] = *(const short8_t*)(vg + (size_t)p*32*2048);
  }
  f32x16 o0 = zero16(), o1 = zero16(), o2 = zero16(), o3 = zero16();
  float m = -1e30f, lsum = 0.f;
  int swz = (q31 & 15) << 4;
  const char* Kr = (const char*)Klds + q31*256;
  const char* Vr = (const char*)Vlds + q31*256;
  #pragma unroll 1
  for (int jt = 0; jt < 16; jt++){
    __syncthreads();               // previous compute done
    #pragma unroll
    for (int p = 0; p < 4; p++){
      *(short8_t*)(Kw + p*4096) = kr[p];
      *(short8_t*)(Vw + p*8192) = vr[p];
    }
    __syncthreads();               // tile visible
    if (jt < 15){                  // issue next tile early (hides under compute)
      #pragma unroll
      for (int p = 0; p < 4; p++){
        kr[p] = *(const short8_t*)(kg + (size_t)((jt+1)*64 + p*16)*128);
        vr[p] = *(const short8_t*)(vg + (size_t)(jt+1)*64 + (size_t)p*32*2048);
      }
    }
    // ---- QK^T (swapped): S^T[kv][q], kv blocks 0-31 (s0) and 32-63 (s1) ----
    f32x16 s0 = zero16(), s1 = zero16();
    __builtin_amdgcn_s_setprio(1);
    #pragma unroll
    for (int s = 0; s < 8; s++){
      int cb = (s*32 + hi16) ^ swz;
      bf16x8 k0 = ldf(Kr + cb);
      bf16x8 k1 = ldf(Kr + cb + 8192);
      s0 = mfma32(k0, qf[s], s0);
      s1 = mfma32(k1, qf[s], s1);
    }
    __builtin_amdgcn_s_setprio(0);
    // ---- online softmax, lane-local (q = lane&31) ----
    float t = fmaxf(s0[0], s1[0]);
    #pragma unroll
    for (int r = 1; r < 16; r++) t = fmaxf(t, fmaxf(s0[r], s1[r]));
    t = fmaxf(t, __shfl_xor(t, 32));
    if (__any(t > m + 8.f)){       // defer-max: rescale only on real growth
      float mn = fmaxf(m, t);
      float cr = __expf(m - mn);
      m = mn;
      lsum *= cr;
      #pragma unroll
      for (int r = 0; r < 16; r++){ o0[r]*=cr; o1[r]*=cr; o2[r]*=cr; o3[r]*=cr; }
    }
    u32 pa[8], pb[8];
    float psum = 0.f;
    #pragma unroll
    for (int i = 0; i < 8; i++){
      float a0 = __expf(s0[2*i] - m), a1 = __expf(s0[2*i+1] - m);
      float b0 = __expf(s1[2*i] - m), b1 = __expf(s1[2*i+1] - m);
      psum += (a0 + a1) + (b0 + b1);
      pa[i] = cvtpk(a0, a1);
      pb[i] = cvtpk(b0, b1);
    }
    lsum += psum;
    // ---- P^T redistribution: one xor-32 swap serves both halves ----
    u32 xa0 = __shfl_xor(hi ? pa[0] : pa[2], 32);
    u32 xa1 = __shfl_xor(hi ? pa[1] : pa[3], 32);
    u32 xa2 = __shfl_xor(hi ? pa[4] : pa[6], 32);
    u32 xa3 = __shfl_xor(hi ? pa[5] : pa[7], 32);
    u32 xb0 = __shfl_xor(hi ? pb[0] : pb[2], 32);
    u32 xb1 = __shfl_xor(hi ? pb[1] : pb[3], 32);
    u32 xb2 = __shfl_xor(hi ? pb[4] : pb[6], 32);
    u32 xb3 = __shfl_xor(hi ? pb[5] : pb[7], 32);
    bf16x8 pf0 = mkfrag(hi?xa0:pa[0], hi?xa1:pa[1], hi?pa[2]:xa0, hi?pa[3]:xa1);
    bf16x8 pf1 = mkfrag(hi?xa2:pa[4], hi?xa3:pa[5], hi?pa[6]:xa2, hi?pa[7]:xa3);
    bf16x8 pf2 = mkfrag(hi?xb0:pb[0], hi?xb1:pb[1], hi?pb[2]:xb0, hi?pb[3]:xb1);
    bf16x8 pf3 = mkfrag(hi?xb2:pb[4], hi?xb3:pb[5], hi?pb[6]:xb2, hi?pb[7]:xb3);
    // ---- PV (swapped): O^T[d][q] += V^T @ P^T ----
    __builtin_amdgcn_s_setprio(1);
    #pragma unroll
    for (int s4 = 0; s4 < 4; s4++){
      int cb = (s4*32 + hi16) ^ swz;
      bf16x8 pf = (s4==0)?pf0:(s4==1)?pf1:(s4==2)?pf2:pf3;
      o0 = mfma32(ldf(Vr + cb),         pf, o0);
      o1 = mfma32(ldf(Vr + cb + 8192),  pf, o1);
      o2 = mfma32(ldf(Vr + cb + 16384), pf, o2);
      o3 = mfma32(ldf(Vr + cb + 24576), pf, o3);
    }
    __builtin_amdgcn_s_setprio(0);
  }
  // ---- epilogue: totals + bf16 partial store ----
  lsum += __shfl_xor(lsum, 32);
  float inv = 1.f / lsum;
  size_t rowq = (size_t)(b*L_) + qrow0 + q31;
  size_t obase = ((size_t)z*BL_ + rowq)*128;
  #pragma unroll
  for (int g = 0; g < 4; g++){
    int dg = g*8 + hi*4;
    uint2 w0 = { cvtpk(o0[4*g]*inv, o0[4*g+1]*inv), cvtpk(o0[4*g+2]*inv, o0[4*g+3]*inv) };
    *(uint2*)&o_part[obase + dg] = w0;
    uint2 w1 = { cvtpk(o1[4*g]*inv, o1[4*g+1]*inv), cvtpk(o1[4*g+2]*inv, o1[4*g+3]*inv) };
    *(uint2*)&o_part[obase + 32 + dg] = w1;
    uint2 w2 = { cvtpk(o2[4*g]*inv, o2[4*g+1]*inv), cvtpk(o2[4*g+2]*inv, o2[4*g+3]*inv) };
    *(uint2*)&o_part[obase + 64 + dg] = w2;
    uint2 w3 = { cvtpk(o3[4*g]*inv, o3[4*g+1]*inv), cvtpk(o3[4*g+2]*inv, o3[4*g+3]*inv) };
    *(uint2*)&o_part[obase + 96 + dg] = w3;
  }
  if (hi == 0){
    float2 mlv = make_float2(m, lsum);
    *(float2*)&ml[((size_t)z*BL_ + rowq)*2] = mlv;
  }
}

// ---------------- K4b: combine split partials ----------------
__global__ __launch_bounds__(256) void attn_combine(const u16* __restrict__ o_part,
    const float* __restrict__ ml, float* __restrict__ attnO){
  int tid = threadIdx.x;
  int row = blockIdx.x*8 + (tid >> 5);
  int d0 = (tid & 31)*4;
  float m_s[NSPLIT], l_s[NSPLIT];
  float M = -1e30f;
  #pragma unroll
  for (int s = 0; s < NSPLIT; s++){
    m_s[s] = ml[((size_t)s*BL_ + row)*2];
    l_s[s] = ml[((size_t)s*BL_ + row)*2 + 1];
    M = fmaxf(M, m_s[s]);
  }
  float Lt = 0.f, w[NSPLIT];
  #pragma unroll
  for (int s = 0; s < NSPLIT; s++){ w[s] = __expf(m_s[s] - M); Lt += l_s[s]*w[s]; }
  float ax=0.f, ay=0.f, az=0.f, aw=0.f;
  #pragma unroll
  for (int s = 0; s < NSPLIT; s++){
    float ws = w[s]*l_s[s];
    uint2 pk = *(const uint2*)&o_part[((size_t)s*BL_ + row)*128 + d0];
    ax += ws*bf2f((u16)(pk.x & 0xffffu));
    ay += ws*bf2f((u16)(pk.x >> 16));
    az += ws*bf2f((u16)(pk.y & 0xffffu));
    aw += ws*bf2f((u16)(pk.y >> 16));
  }
  float inv = 1.f/Lt;
  float4 outv = {ax*inv, ay*inv, az*inv, aw*inv};
  *(float4*)&attnO[(size_t)row*128 + d0] = outv;
}

// ---------------- K5: (u*V) @ w_o + b_o -> outbl bf16 (b,l,256) ----------------
__global__ __launch_bounds__(256) void gemm_out(const float* __restrict__ attnO,
    const float* __restrict__ u, const u16* __restrict__ woT,
    const float* __restrict__ b_o, u16* __restrict__ outbl){
  __shared__ u16 atile[64*128];
  int b = blockIdx.y, lt = blockIdx.x;
  int tid = threadIdx.x;
  size_t rowbase = (size_t)(b*L_) + lt*64;
  for (int i = 0; i < 8; i++){
    int idx = tid + 256*i;
    int row = idx >> 5, d0 = (idx & 31)*4;
    size_t gofs = (rowbase + row)*128 + d0;
    float4 av = *(const float4*)&attnO[gofs];
    float4 uv = *(const float4*)&u[gofs];
    uint2 pk;
    pk.x = (u32)f2bf(av.x*uv.x) | ((u32)f2bf(av.y*uv.y) << 16);
    pk.y = (u32)f2bf(av.z*uv.z) | ((u32)f2bf(av.w*uv.w) << 16);
    int byte = (row*256 + d0*2) ^ ((row & 7) << 4);
    *(uint2*)((char*)atile + byte) = pk;
  }
  __syncthreads();
  int lane = tid & 63, wave = tid >> 6;
  int l15 = lane & 15, lg = lane >> 4;
  int n0 = wave*64;
  f32x4 zero = {0.f,0.f,0.f,0.f};
  f32x4 acc[4][4];
  for (int m=0;m<4;m++) for(int n=0;n<4;n++) acc[m][n]=zero;
  for (int ks = 0; ks < 4; ks++){
    bf16x8 a[4];
    #pragma unroll
    for (int m = 0; m < 4; m++){
      int row = m*16 + l15;
      int byte = (row*256 + ks*64 + lg*16) ^ ((row&7)<<4);
      a[m] = __builtin_bit_cast(bf16x8, *(const short8_t*)((char*)atile + byte));
    }
    #pragma unroll
    for (int n = 0; n < 4; n++){
      int col = n0 + n*16 + l15;
      bf16x8 bf = ld_bf8(&woT[col*128 + ks*32 + lg*8]);
      #pragma unroll
      for (int m = 0; m < 4; m++) acc[m][n] = mfma16(a[m], bf, acc[m][n]);
    }
  }
  for (int n = 0; n < 4; n++){
    int col = n0 + n*16 + l15;
    float bias = b_o[col];
    for (int m = 0; m < 4; m++)
      #pragma unroll
      for (int r = 0; r < 4; r++){
        size_t row = rowbase + m*16 + lg*4 + r;
        outbl[row*256 + col] = f2bf(acc[m][n][r] + bias);
      }
  }
}

// ---------------- K6: proj GEMM + residual/skip epilogue ----------------
__global__ __launch_bounds__(256) void gemm_proj(const u16* __restrict__ outbl,
    const u16* __restrict__ wp_bf, const float* __restrict__ b_p,
    const float* __restrict__ x, float* __restrict__ outp){
  __shared__ u16 atile[32*256];
  int b = blockIdx.y, lt = blockIdx.x; // 64 tiles of 32 rows
  int tid = threadIdx.x;
  size_t rowbase = (size_t)(b*L_) + lt*32;
  for (int i = 0; i < 4; i++){
    int chunk = tid + 256*i;
    int row = chunk >> 5, kc = chunk & 31;
    int byte = (row*512 + kc*16) ^ ((row & 7) << 4);
    *(short8_t*)((char*)atile + byte) = *(const short8_t*)&outbl[(rowbase + row)*256 + kc*8];
  }
  __syncthreads();
  int lane = tid & 63, wave = tid >> 6;
  int l15 = lane & 15, lg = lane >> 4;
  int n0 = wave*128;
  f32x4 zero = {0.f,0.f,0.f,0.f};
  f32x4 acc[2][8];
  for (int m=0;m<2;m++) for(int n=0;n<8;n++) acc[m][n]=zero;
  for (int ks = 0; ks < 8; ks++){
    bf16x8 a[2];
    #pragma unroll
    for (int m = 0; m < 2; m++){
      int row = m*16 + l15;
      int byte = (row*512 + ks*64 + lg*16) ^ ((row&7)<<4);
      a[m] = __builtin_bit_cast(bf16x8, *(const short8_t*)((char*)atile + byte));
    }
    #pragma unroll
    for (int n = 0; n < 8; n++){
      int col = n0 + n*16 + l15;
      bf16x8 bf = ld_bf8(&wp_bf[col*256 + ks*32 + lg*8]);
      #pragma unroll
      for (int m = 0; m < 2; m++) acc[m][n] = mfma16(a[m], bf, acc[m][n]);
    }
  }
  const float inv_s2 = 0.70710678118654752f;
  for (int n = 0; n < 8; n++){
    int o = n0 + n*16 + l15;
    float bias = b_p[o];
    for (int m = 0; m < 2; m++){
      int lofs = lt*32 + m*16 + lg*4;
      float4 v;
      v.x = acc[m][n][0] + bias; v.y = acc[m][n][1] + bias;
      v.z = acc[m][n][2] + bias; v.w = acc[m][n][3] + bias;
      if (o < 256){
        size_t xofs = ((size_t)b*256 + o)*L_ + lofs;
        float4 xv = *(const float4*)&x[xofs];
        v.x = (xv.x + v.x)*inv_s2; v.y = (xv.y + v.y)*inv_s2;
        v.z = (xv.z + v.z)*inv_s2; v.w = (xv.w + v.w)*inv_s2;
        *(float4*)&outp[xofs] = v;
      } else {
        size_t oofs = (size_t)B_*256*L_ + ((size_t)b*256 + (o-256))*L_ + lofs;
        *(float4*)&outp[oofs] = v;
      }
    }
  }
}

extern "C" void kernel_launch(void* const* d_in, const int* in_sizes, int n_in,
                              void* d_out, int out_size, void* d_ws, size_t ws_size,
                              hipStream_t stream){
  const float* x    = (const float*)d_in[0];
  const float* ln_g = (const float*)d_in[1];
  const float* ln_b = (const float*)d_in[2];
  const float* w_h  = (const float*)d_in[3];
  const float* b_h  = (const float*)d_in[4];
  const float* w_qk = (const float*)d_in[5];
  const float* b_qk = (const float*)d_in[6];
  const float* gamma= (const float*)d_in[7];
  const float* beta = (const float*)d_in[8];
  const float* w_o  = (const float*)d_in[9];
  const float* b_o  = (const float*)d_in[10];
  const float* w_p  = (const float*)d_in[11];
  const float* b_p  = (const float*)d_in[12];
  char* ws = (char*)d_ws;
  u16*  hidz   = (u16*)(ws + 0);                 // 25,165,824 (dead after pointwise)
  u16*  o_part = (u16*)(ws + 0);                 // 16,777,216 (NSPLIT*BL*128 bf16)
  u16*  outbl  = (u16*)(ws + 0);                 // 16,777,216 (after combine)
  u16*  normed = (u16*)(ws + 25165824);          // 16,777,216
  float* ml    = (float*)(ws + 33554432);        //    524,288 (NSPLIT*BL*2 f32)
  u16*  qm     = (u16*)(ws + 41943040);          //  8,388,608
  u16*  km     = (u16*)(ws + 50331648);          //  8,388,608
  u16*  vT     = (u16*)(ws + 58720256);          //  8,388,608
  float* u     = (float*)(ws + 67108864);        // 16,777,216
  float* attnO = (float*)(ws + 83886080);        // 16,777,216
  u16*  wT1    = (u16*)(ws + 100663296);         //    196,608
  u16*  woT    = (u16*)(ws + 100663296 + 196608);//     65,536
  u16*  wp_bf  = (u16*)(ws + 100663296 + 262144);//    262,144
  float* bias384=(float*)(ws + 100663296 + 524288); //   2,048
  float* ctab  = (float*)(ws + 100663296 + 526336); // 524,288
  float* stab  = ctab + 2048*64;                    // 524,288
  float* outp  = (float*)d_out;

  prep_weights<<<dim3(512),dim3(256),0,stream>>>(w_h,w_qk,w_o,w_p,b_h,b_qk,wT1,woT,wp_bf,bias384);
  prep_rope<<<dim3(512),dim3(256),0,stream>>>(ctab,stab);
  ln_kernel<<<dim3(32,16),dim3(256),0,stream>>>(x,ln_g,ln_b,normed);
  gemm_hid<<<dim3(32,16),dim3(256),0,stream>>>(normed,wT1,bias384,hidz);
  pointwise_kernel<<<dim3(32,16),dim3(256),0,stream>>>(hidz,ctab,stab,gamma,beta,u,vT,qm,km);
  attn_split<<<dim3(16,16,NSPLIT),dim3(256),0,stream>>>(qm,km,vT,o_part,ml);
  attn_combine<<<dim3(BL_/8),dim3(256),0,stream>>>(o_part,ml,attnO);
  gemm_out<<<dim3(32,16),dim3(256),0,stream>>>(attnO,u,woT,b_o,outbl);
  gemm_proj<<<dim3(64,16),dim3(256),0,stream>>>(outbl,wp_bf,b_p,x,outp);
}

// Round 5
// 173.836 us; speedup vs baseline: 2.3998x; 1.1439x over previous
//
#include <hip/hip_runtime.h>
#include <hip/hip_bf16.h>
#include <math.h>

#define DEVINL __device__ __forceinline__

typedef __bf16 bf16x8 __attribute__((ext_vector_type(8)));
typedef short short8_t __attribute__((ext_vector_type(8)));
typedef float f32x4 __attribute__((ext_vector_type(4)));
typedef float f32x16 __attribute__((ext_vector_type(16)));
typedef unsigned short u16;
typedef unsigned int u32;

#define B_ 16
#define L_ 2048
#define DIM_ 256
#define BL_ (B_*L_)
#define NSPLIT 2

DEVINL u16 f2bf(float f){
  __hip_bfloat16 h = __float2bfloat16(f);
  return __builtin_bit_cast(u16, h);
}
DEVINL float bf2f(u16 u){
  __hip_bfloat16 h = __builtin_bit_cast(__hip_bfloat16, u);
  return __bfloat162float(h);
}
DEVINL float siluf(float x){ return x / (1.f + __expf(-x)); }
DEVINL f32x4 mfma16(bf16x8 a, bf16x8 b, f32x4 c){
  return __builtin_amdgcn_mfma_f32_16x16x32_bf16(a, b, c, 0, 0, 0);
}
DEVINL f32x16 mfma32(bf16x8 a, bf16x8 b, f32x16 c){
  return __builtin_amdgcn_mfma_f32_32x32x16_bf16(a, b, c, 0, 0, 0);
}
DEVINL bf16x8 ld_bf8(const u16* p){
  return __builtin_bit_cast(bf16x8, *(const short8_t*)p);
}
DEVINL bf16x8 ldf(const char* p){
  return __builtin_bit_cast(bf16x8, *(const short8_t*)p);
}
DEVINL u32 cvtpk(float lo, float hi_){
  u32 r;
  asm("v_cvt_pk_bf16_f32 %0, %1, %2" : "=v"(r) : "v"(lo), "v"(hi_));
  return r;
}
DEVINL bf16x8 mkfrag(u32 a, u32 b, u32 c, u32 d){
  union { u32 w[4]; bf16x8 v; } u_;
  u_.w[0]=a; u_.w[1]=b; u_.w[2]=c; u_.w[3]=d;
  return u_.v;
}
DEVINL f32x16 zero16(){
  f32x16 v;
  #pragma unroll
  for (int i = 0; i < 16; i++) v[i] = 0.f;
  return v;
}

// ---------------- P1: weight prep: wT1 = [w_h|w_qk]^T bf16, bias384 ----------
__global__ __launch_bounds__(256) void prep_weights(
    const float* __restrict__ w_h, const float* __restrict__ w_qk,
    const float* __restrict__ b_h, const float* __restrict__ b_qk,
    u16* __restrict__ wT1, float* __restrict__ bias384){
  int idx = blockIdx.x*256 + threadIdx.x;
  const int total = 384*256 + 384;
  for (; idx < total; idx += gridDim.x*256){
    int i = idx;
    if (i < 384*256){
      int n = i >> 8, k = i & 255;
      float v = (n < 256) ? w_h[k*256 + n] : w_qk[k*128 + (n-256)];
      wT1[i] = f2bf(v);
    } else {
      i -= 384*256;
      bias384[i] = (i < 256) ? b_h[i] : b_qk[i-256];
    }
  }
}

// ---------------- P1b: fused output weights: wf[o][h] = sum_c w_o[h,c]*w_p[o,c]
__global__ __launch_bounds__(256) void prep_fused(const float* __restrict__ w_o,
    const float* __restrict__ w_p, const float* __restrict__ b_o,
    const float* __restrict__ b_p, u16* __restrict__ wf,
    float* __restrict__ bias_f){
  int idx = blockIdx.x*256 + threadIdx.x;   // 512*128
  int o = idx >> 7, h = idx & 127;
  const float* wpr = w_p + o*256;
  const float* wor = w_o + h*256;
  float s = 0.f;
  for (int c = 0; c < 256; c += 4){
    float4 a = *(const float4*)&wpr[c];
    float4 bb = *(const float4*)&wor[c];
    s += a.x*bb.x + a.y*bb.y + a.z*bb.z + a.w*bb.w;
  }
  wf[o*128 + h] = f2bf(s);
  if (h == 0){
    float t = b_p[o];
    for (int c = 0; c < 256; c++) t += b_o[c]*wpr[c];
    bias_f[o] = t;
  }
}

// ---------------- P2: rope tables ----------------
__global__ __launch_bounds__(256) void prep_rope(float* __restrict__ ctab, float* __restrict__ stab){
  int idx = blockIdx.x*256 + threadIdx.x; // 2048*64
  if (idx >= 2048*64) return;
  int l = idx >> 6, f = idx & 63;
  float inv = powf(10000.f, -(float)(2*f) * (1.f/128.f));
  float ang = (float)l * inv;
  ctab[idx] = cosf(ang);
  stab[idx] = sinf(ang);
}

// ---------------- K1: layernorm (b,c,l)->bf16 (b,l,c) ----------------
__global__ __launch_bounds__(256) void ln_kernel(const float* __restrict__ x,
    const float* __restrict__ ln_g, const float* __restrict__ ln_b,
    u16* __restrict__ normed){
  __shared__ float xs[256][65];
  __shared__ float redsum[4][64], redsq[4][64];
  __shared__ float mu_s[64], rs_s[64];
  int b = blockIdx.y, lt = blockIdx.x;
  int tid = threadIdx.x;
  int tx = tid & 63, ty = tid >> 6;
  size_t xbase = (size_t)b*DIM_*L_ + (size_t)lt*64;
  float s = 0.f, s2 = 0.f;
  for (int c = ty; c < 256; c += 4){
    float v = x[xbase + (size_t)c*L_ + tx];
    xs[c][tx] = v;
    s += v; s2 += v*v;
  }
  redsum[ty][tx] = s; redsq[ty][tx] = s2;
  __syncthreads();
  if (ty == 0){
    float ss = redsum[0][tx]+redsum[1][tx]+redsum[2][tx]+redsum[3][tx];
    float qq = redsq[0][tx]+redsq[1][tx]+redsq[2][tx]+redsq[3][tx];
    float mu = ss * (1.f/256.f);
    float var = qq * (1.f/256.f) - mu*mu;
    mu_s[tx] = mu;
    rs_s[tx] = rsqrtf(var + 1e-5f);
  }
  __syncthreads();
  for (int i = 0; i < 8; i++){
    int chunk = tid + 256*i;
    int l = chunk >> 5, c0 = (chunk & 31) * 8;
    float mu = mu_s[l], rs = rs_s[l];
    short8_t outv;
    #pragma unroll
    for (int j = 0; j < 8; j++){
      int c = c0 + j;
      float v = (xs[c][l] - mu) * rs * ln_g[c] + ln_b[c];
      outv[j] = (short)f2bf(v);
    }
    *(short8_t*)&normed[((size_t)(b*L_) + lt*64 + l)*256 + c0] = outv;
  }
}

// ---------------- K2: GEMM1 normed @ [w_h | w_qk] + bias -> hidz bf16 (b,l,384)
__global__ __launch_bounds__(256) void gemm_hid(const u16* __restrict__ normed,
    const u16* __restrict__ wT1, const float* __restrict__ bias384,
    u16* __restrict__ hidz){
  __shared__ u16 atile[64*256];
  int b = blockIdx.y, lt = blockIdx.x;
  int tid = threadIdx.x;
  for (int i = 0; i < 8; i++){
    int chunk = tid + 256*i;
    int row = chunk >> 5, kc = chunk & 31;
    int byte = (row*512 + kc*16) ^ ((row & 7) << 4);
    *(short8_t*)((char*)atile + byte) =
        *(const short8_t*)&normed[((size_t)(b*L_) + lt*64 + row)*256 + kc*8];
  }
  __syncthreads();
  int lane = tid & 63, wave = tid >> 6;
  int l15 = lane & 15, lg = lane >> 4;
  int n0 = wave * 96;
  f32x4 zero = {0.f,0.f,0.f,0.f};
  f32x4 acc[4][6];
  for (int m=0;m<4;m++) for (int n=0;n<6;n++) acc[m][n]=zero;
  for (int ks = 0; ks < 8; ks++){
    bf16x8 a[4];
    #pragma unroll
    for (int m = 0; m < 4; m++){
      int row = m*16 + l15;
      int byte = (row*512 + ks*64 + lg*16) ^ ((row & 7) << 4);
      a[m] = __builtin_bit_cast(bf16x8, *(const short8_t*)((char*)atile + byte));
    }
    #pragma unroll
    for (int n = 0; n < 6; n++){
      int col = n0 + n*16 + l15;
      bf16x8 bfrag = ld_bf8(&wT1[col*256 + ks*32 + lg*8]);
      #pragma unroll
      for (int m = 0; m < 4; m++)
        acc[m][n] = mfma16(a[m], bfrag, acc[m][n]);
    }
  }
  for (int n = 0; n < 6; n++){
    int col = n0 + n*16 + l15;
    float bias = bias384[col];
    for (int m = 0; m < 4; m++)
      #pragma unroll
      for (int r = 0; r < 4; r++){
        size_t row = (size_t)(b*L_) + lt*64 + m*16 + lg*4 + r;
        hidz[row*384 + col] = f2bf(acc[m][n][r] + bias);
      }
  }
}

// ---------------- K3: pointwise silu / rope -> u_bf, vT, q (1/L scaled), k ----
__global__ __launch_bounds__(256) void pointwise_kernel(const u16* __restrict__ hidz,
    const float* __restrict__ ctab, const float* __restrict__ stab,
    const float* __restrict__ gamma, const float* __restrict__ beta,
    u16* __restrict__ u_bf, u16* __restrict__ vT,
    u16* __restrict__ qm, u16* __restrict__ km){
  __shared__ u16 vs[64][130];
  int b = blockIdx.y, lt = blockIdx.x;
  int tid = threadIdx.x;
  size_t rowbase = (size_t)(b*L_) + lt*64;
  // u = silu(hid[128:256]) -> bf16 packed, and v rows -> LDS
  for (int i = 0; i < 16; i++){
    int idx = tid + 256*i;                 // 4096 units: l(64) x d2(64)
    int l = idx >> 6, d2 = idx & 63;
    size_t row = rowbase + l;
    u32 hv = *(const u32*)&hidz[row*384 + 128 + 2*d2];
    float a0 = siluf(bf2f((u16)(hv & 0xffffu)));
    float a1 = siluf(bf2f((u16)(hv >> 16)));
    *(u32*)&u_bf[row*128 + 2*d2] = cvtpk(a0, a1);
    u32 vv = *(const u32*)&hidz[row*384 + 2*d2];
    *(u32*)&vs[l][2*d2] = vv;
  }
  __syncthreads();
  for (int i = 0; i < 4; i++){
    int chunk = tid + 256*i;
    int d = chunk >> 3, lc = (chunk & 7)*8;
    short8_t vv;
    #pragma unroll
    for (int j = 0; j < 8; j++)
      vv[j] = (short)f2bf(siluf(bf2f(vs[lc + j][d])));
    *(short8_t*)&vT[((size_t)b*128 + d)*2048 + lt*64 + lc] = vv;
  }
  const float inv_L = 1.f/(float)L_;
  for (int i = 0; i < 16; i++){
    int idx = tid + 256*i;
    int l = idx >> 6, f = idx & 63;
    size_t row = rowbase + l;
    u32 zz = *(const u32*)&hidz[row*384 + 256 + 2*f];
    float z1 = siluf(bf2f((u16)(zz & 0xffffu)));
    float z2 = siluf(bf2f((u16)(zz >> 16)));
    int gl = lt*64 + l;
    float c = ctab[gl*64 + f], s = stab[gl*64 + f];
    float q1 = z1*gamma[2*f]   + beta[2*f];
    float q2 = z2*gamma[2*f+1] + beta[2*f+1];
    u32 qp = (u32)f2bf((q1*c - q2*s)*inv_L) | ((u32)f2bf((q1*s + q2*c)*inv_L) << 16);
    *(u32*)&qm[row*128 + 2*f] = qp;
    float k1 = z1*gamma[128 + 2*f]   + beta[128 + 2*f];
    float k2 = z2*gamma[128 + 2*f+1] + beta[128 + 2*f+1];
    u32 kp = (u32)f2bf(k1*c - k2*s) | ((u32)f2bf(k1*s + k2*c) << 16);
    *(u32*)&km[row*128 + 2*f] = kp;
  }
}

// ---------------- K4: flash attention, 32x32 swapped-operand, split-KV --------
__global__ __launch_bounds__(256, 2) void attn_split(const u16* __restrict__ qm,
    const u16* __restrict__ km, const u16* __restrict__ vT,
    u16* __restrict__ o_part, float* __restrict__ ml){
  __shared__ u16 Klds[64*128];    // [kv=64][d=128] rows 256B, swz ^((row&15)<<4)
  __shared__ u16 Vlds[128*128];   // [d=128][kv 64 used] rows padded to 256B, same swz
  int b = blockIdx.y, qt = blockIdx.x, z = blockIdx.z;
  int tid = threadIdx.x;
  int lane = tid & 63, wave = tid >> 6;
  int q31 = lane & 31, hi = lane >> 5;
  int hi16 = hi << 4;
  int qrow0 = qt*128 + wave*32;
  size_t qbase = ((size_t)(b*L_) + qrow0 + q31)*128 + hi*8;
  bf16x8 qf[8];
  #pragma unroll
  for (int s = 0; s < 8; s++)
    qf[s] = ld_bf8(&qm[qbase + s*16]);
  int krow = tid >> 4, kcol = tid & 15;
  int vd   = tid >> 3, vcol = tid & 7;
  const u16* kg = km + ((size_t)(b*L_) + z*1024 + krow)*128 + kcol*8;
  const u16* vg = vT + ((size_t)b*128 + vd)*2048 + (size_t)z*1024 + vcol*8;
  char* Kw = (char*)Klds + krow*256 + ((kcol*16) ^ ((krow & 15) << 4));
  char* Vw = (char*)Vlds + vd*256  + ((vcol*16) ^ ((vd  & 15) << 4));
  short8_t kr[4], vr[4];
  #pragma unroll
  for (int p = 0; p < 4; p++){
    kr[p] = *(const short8_t*)(kg + (size_t)p*16*128);
    vr[p] = *(const short8_t*)(vg + (size_t)p*32*2048);
  }
  f32x16 o0 = zero16(), o1 = zero16(), o2 = zero16(), o3 = zero16();
  float m = -1e30f, lsum = 0.f;
  int swz = (q31 & 15) << 4;
  const char* Kr = (const char*)Klds + q31*256;
  const char* Vr = (const char*)Vlds + q31*256;
  #pragma unroll 1
  for (int jt = 0; jt < 16; jt++){
    __syncthreads();
    #pragma unroll
    for (int p = 0; p < 4; p++){
      *(short8_t*)(Kw + p*4096) = kr[p];
      *(short8_t*)(Vw + p*8192) = vr[p];
    }
    __syncthreads();
    if (jt < 15){
      #pragma unroll
      for (int p = 0; p < 4; p++){
        kr[p] = *(const short8_t*)(kg + (size_t)((jt+1)*64 + p*16)*128);
        vr[p] = *(const short8_t*)(vg + (size_t)(jt+1)*64 + (size_t)p*32*2048);
      }
    }
    f32x16 s0 = zero16(), s1 = zero16();
    __builtin_amdgcn_s_setprio(1);
    #pragma unroll
    for (int s = 0; s < 8; s++){
      int cb = (s*32 + hi16) ^ swz;
      bf16x8 k0 = ldf(Kr + cb);
      bf16x8 k1 = ldf(Kr + cb + 8192);
      s0 = mfma32(k0, qf[s], s0);
      s1 = mfma32(k1, qf[s], s1);
    }
    __builtin_amdgcn_s_setprio(0);
    float t = fmaxf(s0[0], s1[0]);
    #pragma unroll
    for (int r = 1; r < 16; r++) t = fmaxf(t, fmaxf(s0[r], s1[r]));
    t = fmaxf(t, __shfl_xor(t, 32));
    if (__any(t > m + 8.f)){
      float mn = fmaxf(m, t);
      float cr = __expf(m - mn);
      m = mn;
      lsum *= cr;
      #pragma unroll
      for (int r = 0; r < 16; r++){ o0[r]*=cr; o1[r]*=cr; o2[r]*=cr; o3[r]*=cr; }
    }
    u32 pa[8], pb[8];
    float psum = 0.f;
    #pragma unroll
    for (int i = 0; i < 8; i++){
      float a0 = __expf(s0[2*i] - m), a1 = __expf(s0[2*i+1] - m);
      float b0 = __expf(s1[2*i] - m), b1 = __expf(s1[2*i+1] - m);
      psum += (a0 + a1) + (b0 + b1);
      pa[i] = cvtpk(a0, a1);
      pb[i] = cvtpk(b0, b1);
    }
    lsum += psum;
    u32 xa0 = __shfl_xor(hi ? pa[0] : pa[2], 32);
    u32 xa1 = __shfl_xor(hi ? pa[1] : pa[3], 32);
    u32 xa2 = __shfl_xor(hi ? pa[4] : pa[6], 32);
    u32 xa3 = __shfl_xor(hi ? pa[5] : pa[7], 32);
    u32 xb0 = __shfl_xor(hi ? pb[0] : pb[2], 32);
    u32 xb1 = __shfl_xor(hi ? pb[1] : pb[3], 32);
    u32 xb2 = __shfl_xor(hi ? pb[4] : pb[6], 32);
    u32 xb3 = __shfl_xor(hi ? pb[5] : pb[7], 32);
    bf16x8 pf0 = mkfrag(hi?xa0:pa[0], hi?xa1:pa[1], hi?pa[2]:xa0, hi?pa[3]:xa1);
    bf16x8 pf1 = mkfrag(hi?xa2:pa[4], hi?xa3:pa[5], hi?pa[6]:xa2, hi?pa[7]:xa3);
    bf16x8 pf2 = mkfrag(hi?xb0:pb[0], hi?xb1:pb[1], hi?pb[2]:xb0, hi?pb[3]:xb1);
    bf16x8 pf3 = mkfrag(hi?xb2:pb[4], hi?xb3:pb[5], hi?pb[6]:xb2, hi?pb[7]:xb3);
    __builtin_amdgcn_s_setprio(1);
    #pragma unroll
    for (int s4 = 0; s4 < 4; s4++){
      int cb = (s4*32 + hi16) ^ swz;
      bf16x8 pf = (s4==0)?pf0:(s4==1)?pf1:(s4==2)?pf2:pf3;
      o0 = mfma32(ldf(Vr + cb),         pf, o0);
      o1 = mfma32(ldf(Vr + cb + 8192),  pf, o1);
      o2 = mfma32(ldf(Vr + cb + 16384), pf, o2);
      o3 = mfma32(ldf(Vr + cb + 24576), pf, o3);
    }
    __builtin_amdgcn_s_setprio(0);
  }
  lsum += __shfl_xor(lsum, 32);
  float inv = 1.f / lsum;
  size_t rowq = (size_t)(b*L_) + qrow0 + q31;
  size_t obase = ((size_t)z*BL_ + rowq)*128;
  #pragma unroll
  for (int g = 0; g < 4; g++){
    int dg = g*8 + hi*4;
    uint2 w0 = { cvtpk(o0[4*g]*inv, o0[4*g+1]*inv), cvtpk(o0[4*g+2]*inv, o0[4*g+3]*inv) };
    *(uint2*)&o_part[obase + dg] = w0;
    uint2 w1 = { cvtpk(o1[4*g]*inv, o1[4*g+1]*inv), cvtpk(o1[4*g+2]*inv, o1[4*g+3]*inv) };
    *(uint2*)&o_part[obase + 32 + dg] = w1;
    uint2 w2 = { cvtpk(o2[4*g]*inv, o2[4*g+1]*inv), cvtpk(o2[4*g+2]*inv, o2[4*g+3]*inv) };
    *(uint2*)&o_part[obase + 64 + dg] = w2;
    uint2 w3 = { cvtpk(o3[4*g]*inv, o3[4*g+1]*inv), cvtpk(o3[4*g+2]*inv, o3[4*g+3]*inv) };
    *(uint2*)&o_part[obase + 96 + dg] = w3;
  }
  if (hi == 0){
    float2 mlv = make_float2(m, lsum);
    *(float2*)&ml[((size_t)z*BL_ + rowq)*2] = mlv;
  }
}

// ---------------- K4b: combine split partials -> bf16 attnO ----------------
__global__ __launch_bounds__(256) void attn_combine(const u16* __restrict__ o_part,
    const float* __restrict__ ml, u16* __restrict__ aO_bf){
  int tid = threadIdx.x;
  int row = blockIdx.x*8 + (tid >> 5);
  int d0 = (tid & 31)*4;
  float m_s[NSPLIT], l_s[NSPLIT];
  float M = -1e30f;
  #pragma unroll
  for (int s = 0; s < NSPLIT; s++){
    m_s[s] = ml[((size_t)s*BL_ + row)*2];
    l_s[s] = ml[((size_t)s*BL_ + row)*2 + 1];
    M = fmaxf(M, m_s[s]);
  }
  float Lt = 0.f, w[NSPLIT];
  #pragma unroll
  for (int s = 0; s < NSPLIT; s++){ w[s] = __expf(m_s[s] - M); Lt += l_s[s]*w[s]; }
  float ax=0.f, ay=0.f, az=0.f, aw=0.f;
  #pragma unroll
  for (int s = 0; s < NSPLIT; s++){
    float ws = w[s]*l_s[s];
    uint2 pk = *(const uint2*)&o_part[((size_t)s*BL_ + row)*128 + d0];
    ax += ws*bf2f((u16)(pk.x & 0xffffu));
    ay += ws*bf2f((u16)(pk.x >> 16));
    az += ws*bf2f((u16)(pk.y & 0xffffu));
    aw += ws*bf2f((u16)(pk.y >> 16));
  }
  float inv = 1.f/Lt;
  uint2 outv = { cvtpk(ax*inv, ay*inv), cvtpk(az*inv, aw*inv) };
  *(uint2*)&aO_bf[(size_t)row*128 + d0] = outv;
}

// ---------------- K5: fused output GEMM: (u*V) @ wf^T + bias_f, residual/skip
// block: b, lt (32 l). ov tile staged once; o streamed 4 x 128 through LDS.
// Swapped mfma32: D[row=o][col=l] -> stores are full 128B lines along l.
__global__ __launch_bounds__(256) void gemm_final(const u16* __restrict__ u_bf,
    const u16* __restrict__ aO_bf, const u16* __restrict__ wf,
    const float* __restrict__ bias_f, const float* __restrict__ x,
    float* __restrict__ outp){
  __shared__ u16 ovs[32*128];     // 8 KB  [l=32][h=128] rows 256B, swz
  __shared__ u16 wlds[128*128];   // 32 KB [o=128][h=128] rows 256B, swz
  int b = blockIdx.y, lt = blockIdx.x;
  int tid = threadIdx.x;
  int lane = tid & 63, wave = tid >> 6;
  int q31 = lane & 31, hi = lane >> 5, hi16 = hi << 4;
  // stage ov = u*attnO tile
  #pragma unroll
  for (int p = 0; p < 2; p++){
    int unit = tid + 256*p;
    int row = unit >> 4, c16 = unit & 15;
    size_t g = ((size_t)(b*L_) + lt*32 + row)*128 + c16*8;
    short8_t uv = *(const short8_t*)&u_bf[g];
    short8_t av = *(const short8_t*)&aO_bf[g];
    u32 pk0 = cvtpk(bf2f((u16)uv[0])*bf2f((u16)av[0]), bf2f((u16)uv[1])*bf2f((u16)av[1]));
    u32 pk1 = cvtpk(bf2f((u16)uv[2])*bf2f((u16)av[2]), bf2f((u16)uv[3])*bf2f((u16)av[3]));
    u32 pk2 = cvtpk(bf2f((u16)uv[4])*bf2f((u16)av[4]), bf2f((u16)uv[5])*bf2f((u16)av[5]));
    u32 pk3 = cvtpk(bf2f((u16)uv[6])*bf2f((u16)av[6]), bf2f((u16)uv[7])*bf2f((u16)av[7]));
    uint4 pkv = {pk0, pk1, pk2, pk3};
    *(uint4*)((char*)ovs + row*256 + ((c16*16) ^ ((row & 15) << 4))) = pkv;
  }
  // prefetch first w chunk (o 0..127)
  short8_t wreg[8];
  #pragma unroll
  for (int p = 0; p < 8; p++){
    int unit = tid + 256*p;
    int row = unit >> 4, c16 = unit & 15;
    wreg[p] = *(const short8_t*)&wf[(size_t)row*128 + c16*8];
  }
  const float inv_s2 = 0.70710678118654752f;
  const char* Ob = (const char*)ovs + q31*256;
  int swzq = (q31 & 15) << 4;
  int l = lt*32 + q31;
  #pragma unroll
  for (int it = 0; it < 4; it++){
    __syncthreads();
    #pragma unroll
    for (int p = 0; p < 8; p++){
      int unit = tid + 256*p;
      int row = unit >> 4, c16 = unit & 15;
      *(short8_t*)((char*)wlds + row*256 + ((c16*16) ^ ((row & 15) << 4))) = wreg[p];
    }
    __syncthreads();
    if (it < 3){
      #pragma unroll
      for (int p = 0; p < 8; p++){
        int unit = tid + 256*p;
        int row = unit >> 4, c16 = unit & 15;
        wreg[p] = *(const short8_t*)&wf[(size_t)((it+1)*128 + row)*128 + c16*8];
      }
    }
    const char* Ab = (const char*)wlds + (wave*32 + q31)*256;
    f32x16 acc = zero16();
    __builtin_amdgcn_s_setprio(1);
    #pragma unroll
    for (int s = 0; s < 8; s++){
      int cb = (s*32 + hi16) ^ swzq;
      acc = mfma32(ldf(Ab + cb), ldf(Ob + cb), acc);
    }
    __builtin_amdgcn_s_setprio(0);
    int obase = it*128 + wave*32 + 4*hi;
    #pragma unroll
    for (int r = 0; r < 16; r++){
      int orow = obase + (r & 3) + 8*(r >> 2);
      float v = acc[r] + bias_f[orow];
      if (orow < 256){
        size_t xo = ((size_t)(b*256 + orow))*L_ + l;
        outp[xo] = (x[xo] + v)*inv_s2;
      } else {
        size_t oo = (size_t)B_*256*L_ + ((size_t)(b*256 + orow - 256))*L_ + l;
        outp[oo] = v;
      }
    }
  }
}

extern "C" void kernel_launch(void* const* d_in, const int* in_sizes, int n_in,
                              void* d_out, int out_size, void* d_ws, size_t ws_size,
                              hipStream_t stream){
  const float* x    = (const float*)d_in[0];
  const float* ln_g = (const float*)d_in[1];
  const float* ln_b = (const float*)d_in[2];
  const float* w_h  = (const float*)d_in[3];
  const float* b_h  = (const float*)d_in[4];
  const float* w_qk = (const float*)d_in[5];
  const float* b_qk = (const float*)d_in[6];
  const float* gamma= (const float*)d_in[7];
  const float* beta = (const float*)d_in[8];
  const float* w_o  = (const float*)d_in[9];
  const float* b_o  = (const float*)d_in[10];
  const float* w_p  = (const float*)d_in[11];
  const float* b_p  = (const float*)d_in[12];
  char* ws = (char*)d_ws;
  u16*  hidz   = (u16*)(ws + 0);                 // 25,165,824 (dead after pointwise)
  u16*  o_part = (u16*)(ws + 0);                 // 16,777,216 (reuse)
  u16*  normed = (u16*)(ws + 25165824);          // 16,777,216
  float* ml    = (float*)(ws + 33554432);        //    524,288
  u16*  qm     = (u16*)(ws + 41943040);          //  8,388,608
  u16*  km     = (u16*)(ws + 50331648);          //  8,388,608
  u16*  vT     = (u16*)(ws + 58720256);          //  8,388,608
  u16*  u_bf   = (u16*)(ws + 67108864);          //  8,388,608
  u16*  aO_bf  = (u16*)(ws + 83886080);          //  8,388,608
  u16*  wT1    = (u16*)(ws + 100663296);         //    196,608
  u16*  w_fused= (u16*)(ws + 100663296 + 196608);//    131,072
  float* bias_f= (float*)(ws + 100663296 + 327680);//     2,048
  float* bias384=(float*)(ws + 100663296 + 524288); //   2,048
  float* ctab  = (float*)(ws + 100663296 + 526336); // 524,288
  float* stab  = ctab + 2048*64;                    // 524,288
  float* outp  = (float*)d_out;

  prep_weights<<<dim3(512),dim3(256),0,stream>>>(w_h,w_qk,b_h,b_qk,wT1,bias384);
  prep_fused<<<dim3(256),dim3(256),0,stream>>>(w_o,w_p,b_o,b_p,w_fused,bias_f);
  prep_rope<<<dim3(512),dim3(256),0,stream>>>(ctab,stab);
  ln_kernel<<<dim3(32,16),dim3(256),0,stream>>>(x,ln_g,ln_b,normed);
  gemm_hid<<<dim3(32,16),dim3(256),0,stream>>>(normed,wT1,bias384,hidz);
  pointwise_kernel<<<dim3(32,16),dim3(256),0,stream>>>(hidz,ctab,stab,gamma,beta,u_bf,vT,qm,km);
  attn_split<<<dim3(16,16,NSPLIT),dim3(256),0,stream>>>(qm,km,vT,o_part,ml);
  attn_combine<<<dim3(BL_/8),dim3(256),0,stream>>>(o_part,ml,aO_bf);
  gemm_final<<<dim3(64,16),dim3(256),0,stream>>>(u_bf,aO_bf,w_fused,bias_f,x,outp);
}